// Round 11
// baseline (282.831 us; speedup 1.0000x reference)
//
#include <hip/hip_runtime.h>

// TransformerClassification: 2-layer PyG TransformerConv GNN on MI355X.
// Round 11: proj1 inner-loop restructure ONLY (group-of-4 K iterations:
// 16 independent W loads in flight + float4 LDS x reads). Round-7 shell
// (64 threads / 16 nodes / block) kept — it beat both r8/r9 rewrites.
// Everything else identical to round-10 (264us).

#define N_NODES 50000
#define N_EDGES 800000
#define IN_F    128
#define HC      64      // heads*ch layer1
#define NH      4
#define CH      16
#define OUTF    7

#define NSB ((N_NODES + 255) / 256)   // 196 scan blocks

// ---------------- DPP helpers ----------------
__device__ __forceinline__ float dpp_add16(float x) {
    int t;
    t = __builtin_amdgcn_update_dpp(0, __float_as_int(x), 0xB1, 0xF, 0xF, false);
    x += __int_as_float(t);
    t = __builtin_amdgcn_update_dpp(0, __float_as_int(x), 0x4E, 0xF, 0xF, false);
    x += __int_as_float(t);
    t = __builtin_amdgcn_update_dpp(0, __float_as_int(x), 0x124, 0xF, 0xF, false);
    x += __int_as_float(t);
    t = __builtin_amdgcn_update_dpp(0, __float_as_int(x), 0x128, 0xF, 0xF, false);
    x += __int_as_float(t);
    return x;
}
__device__ __forceinline__ float dpp_max16(float x) {
    int t;
    t = __builtin_amdgcn_update_dpp(0, __float_as_int(x), 0xB1, 0xF, 0xF, false);
    x = fmaxf(x, __int_as_float(t));
    t = __builtin_amdgcn_update_dpp(0, __float_as_int(x), 0x4E, 0xF, 0xF, false);
    x = fmaxf(x, __int_as_float(t));
    t = __builtin_amdgcn_update_dpp(0, __float_as_int(x), 0x124, 0xF, 0xF, false);
    x = fmaxf(x, __int_as_float(t));
    t = __builtin_amdgcn_update_dpp(0, __float_as_int(x), 0x128, 0xF, 0xF, false);
    x = fmaxf(x, __int_as_float(t));
    return x;
}
__device__ __forceinline__ float dpp_add4(float x) {
    int t;
    t = __builtin_amdgcn_update_dpp(0, __float_as_int(x), 0xB1, 0xF, 0xF, false);
    x += __int_as_float(t);
    t = __builtin_amdgcn_update_dpp(0, __float_as_int(x), 0x4E, 0xF, 0xF, false);
    x += __int_as_float(t);
    return x;
}

// ---------------------------------------------------------------- init: zero the histogram
__global__ __launch_bounds__(256) void init_kernel(int* __restrict__ count)
{
    int i = blockIdx.x * 256 + threadIdx.x;
    if (i < N_NODES) count[i] = 0;
}

// ---------------------------------------------------------------- layer1 node projections
// 16 nodes/block, 64 threads (one per output column). K processed in groups
// of 4: 16 independent W loads issued together; x read as float4 from LDS.
#define P1_NB 16
__global__ __launch_bounds__(64) void proj1_kernel(
    const float* __restrict__ x,
    const float* __restrict__ Wq, const float* __restrict__ bq,
    const float* __restrict__ Wk, const float* __restrict__ bk,
    const float* __restrict__ Wv, const float* __restrict__ bv,
    const float* __restrict__ Ws, const float* __restrict__ bs,
    float* __restrict__ q1, float* __restrict__ k1,
    float* __restrict__ v1, float* __restrict__ s1)
{
    __shared__ float xs[P1_NB][IN_F];
    const int t  = threadIdx.x;          // 0..63 = output column
    const int n0 = blockIdx.x * P1_NB;

    for (int j = t; j < P1_NB * IN_F; j += 64)
        xs[j >> 7][j & 127] = x[(size_t)n0 * IN_F + j];
    __syncthreads();

    float aq[P1_NB], ak[P1_NB], av[P1_NB], as_[P1_NB];
#pragma unroll
    for (int n = 0; n < P1_NB; n++) { aq[n] = ak[n] = av[n] = as_[n] = 0.f; }

    for (int i0 = 0; i0 < IN_F; i0 += 4) {
        // 16 independent W loads (rows i0..i0+3 x 4 matrices, column t)
        const float* wqp = Wq + (size_t)i0 * HC + t;
        const float* wkp = Wk + (size_t)i0 * HC + t;
        const float* wvp = Wv + (size_t)i0 * HC + t;
        const float* wsp = Ws + (size_t)i0 * HC + t;
        float wq0 = wqp[0], wq1 = wqp[HC], wq2 = wqp[2*HC], wq3 = wqp[3*HC];
        float wk0 = wkp[0], wk1 = wkp[HC], wk2 = wkp[2*HC], wk3 = wkp[3*HC];
        float wv0 = wvp[0], wv1 = wvp[HC], wv2 = wvp[2*HC], wv3 = wvp[3*HC];
        float ws0 = wsp[0], ws1 = wsp[HC], ws2 = wsp[2*HC], ws3 = wsp[3*HC];

#pragma unroll
        for (int n = 0; n < P1_NB; n++) {
            float4 xv = *(const float4*)&xs[n][i0];   // b128 broadcast read
            aq[n]  += xv.x * wq0 + xv.y * wq1 + xv.z * wq2 + xv.w * wq3;
            ak[n]  += xv.x * wk0 + xv.y * wk1 + xv.z * wk2 + xv.w * wk3;
            av[n]  += xv.x * wv0 + xv.y * wv1 + xv.z * wv2 + xv.w * wv3;
            as_[n] += xv.x * ws0 + xv.y * ws1 + xv.z * ws2 + xv.w * ws3;
        }
    }
    float bqv = bq[t], bkv = bk[t], bvv = bv[t], bsv = bs[t];
#pragma unroll
    for (int n = 0; n < P1_NB; n++) {
        size_t o = (size_t)(n0 + n) * HC + t;
        q1[o] = aq[n] + bqv; k1[o] = ak[n] + bkv;
        v1[o] = av[n] + bvv; s1[o] = as_[n] + bsv;
    }
}

// ---------------------------------------------------------------- histogram of dst
__global__ __launch_bounds__(256) void hist_kernel(
    const int* __restrict__ ei, int* __restrict__ count)
{
    int e = blockIdx.x * 256 + threadIdx.x;
    if (e < N_EDGES) atomicAdd(count + ei[N_EDGES + e], 1);
}

// ---------------------------------------------------------------- scan phase 1
__global__ __launch_bounds__(256) void scan1_kernel(
    const int* __restrict__ count, int* __restrict__ pre, int* __restrict__ bsum)
{
    __shared__ int sdata[256];
    const int t = threadIdx.x;
    const int i = blockIdx.x * 256 + t;
    int v = (i < N_NODES) ? count[i] : 0;
    sdata[t] = v;
    __syncthreads();
    for (int d = 1; d < 256; d <<= 1) {
        int u = (t >= d) ? sdata[t - d] : 0;
        __syncthreads();
        sdata[t] += u;
        __syncthreads();
    }
    if (i < N_NODES) pre[i] = sdata[t] - v;
    if (t == 255) bsum[blockIdx.x] = sdata[255];
}

// ---------------------------------------------------------------- scan phase 2 (1 block)
__global__ __launch_bounds__(256) void scan2_kernel(
    int* __restrict__ bsum, int* __restrict__ bofs)
{
    __shared__ int sdata[256];
    const int t = threadIdx.x;
    int v = (t < NSB) ? bsum[t] : 0;
    sdata[t] = v;
    __syncthreads();
    for (int d = 1; d < 256; d <<= 1) {
        int u = (t >= d) ? sdata[t - d] : 0;
        __syncthreads();
        sdata[t] += u;
        __syncthreads();
    }
    if (t < NSB) bofs[t] = sdata[t] - v;
}

// ---------------------------------------------------------------- scan phase 3
__global__ __launch_bounds__(256) void scan3_kernel(
    const int* __restrict__ pre, const int* __restrict__ bofs,
    int* __restrict__ offs, int* __restrict__ cursor)
{
    const int i = blockIdx.x * 256 + threadIdx.x;
    if (i < N_NODES) {
        int o = pre[i] + bofs[i >> 8];
        offs[i] = o; cursor[i] = o;
    }
    if (i == 0) offs[N_NODES] = N_EDGES;
}

// ---------------------------------------------------------------- scatter: one packed 16B record per edge
__global__ __launch_bounds__(256) void scatter_kernel(
    const int* __restrict__ ei, const float* __restrict__ ea,
    int* __restrict__ cursor, float4* __restrict__ erec)
{
    int e = blockIdx.x * 256 + threadIdx.x;
    if (e >= N_EDGES) return;
    int dst = ei[N_EDGES + e];
    int pos = atomicAdd(cursor + dst, 1);
    float4 r;
    r.x = __int_as_float(ei[e]);
    r.y = ea[(size_t)e * 2];
    r.z = ea[(size_t)e * 2 + 1];
    r.w = 0.f;
    erec[pos] = r;
}

// ---------------------------------------------------------------- layer1 attention: one wave per dst node
// 4 edges per wave (g = lane>>4), 16 lanes per edge (s = lane&15 owns
// channels 4s..4s+3 as float4). Head h = s>>2 -> dot reduce = DPP quad sum.
__global__ __launch_bounds__(256) void attn1_kernel(
    const int* __restrict__ offs, const float4* __restrict__ erec,
    const float* __restrict__ We,
    const float* __restrict__ q1, const float* __restrict__ k1,
    const float* __restrict__ v1, const float* __restrict__ s1,
    float* __restrict__ h)
{
    int n    = (blockIdx.x * 256 + threadIdx.x) >> 6;
    int lane = threadIdx.x & 63;
    if (n >= N_NODES) return;
    const int g = lane >> 4;     // edge slot 0..3
    const int s = lane & 15;     // channel quad: channels 4s..4s+3

    const float4 qv  = *(const float4*)(q1 + (size_t)n * HC + s * 4);
    const float4 We0 = *(const float4*)(We + s * 4);
    const float4 We1 = *(const float4*)(We + HC + s * 4);
    const int beg = offs[n], end = offs[n + 1];

    float m = -3.402823466e38f, l = 0.f;
    float4 acc = make_float4(0.f, 0.f, 0.f, 0.f);

    for (int base = beg; base < end; base += 4) {
        int i = base + g;
        bool valid = (i < end);
        float4 r = erec[valid ? i : beg];
        int src = __float_as_int(r.x);
        size_t b = (size_t)src * HC + s * 4;
        float4 kk = *(const float4*)(k1 + b);
        float4 vv = *(const float4*)(v1 + b);
        float4 ec = make_float4(r.y * We0.x + r.z * We1.x,
                                r.y * We0.y + r.z * We1.y,
                                r.y * We0.z + r.z * We1.z,
                                r.y * We0.w + r.z * We1.w);
        float d = qv.x * (kk.x + ec.x) + qv.y * (kk.y + ec.y)
                + qv.z * (kk.z + ec.z) + qv.w * (kk.w + ec.w);
        d = dpp_add4(d);                          // head dot (16 channels)
        float logit = valid ? d * 0.25f : -3.402823466e38f;   // 1/sqrt(16)
        float mn = fmaxf(m, logit);
        float sm = __expf(m - mn);
        float pe = valid ? __expf(logit - mn) : 0.f;
        l = l * sm + pe;
        acc.x = acc.x * sm + pe * (vv.x + ec.x);
        acc.y = acc.y * sm + pe * (vv.y + ec.y);
        acc.z = acc.z * sm + pe * (vv.z + ec.z);
        acc.w = acc.w * sm + pe * (vv.w + ec.w);
        m = mn;
    }

    if (end > beg) {
        float M = fmaxf(m, __shfl_xor(m, 16));
        M = fmaxf(M, __shfl_xor(M, 32));
        float sc = __expf(m - M);                 // empty group: -inf -> 0
        l *= sc; acc.x *= sc; acc.y *= sc; acc.z *= sc; acc.w *= sc;
        l += __shfl_xor(l, 16);  l += __shfl_xor(l, 32);
        acc.x += __shfl_xor(acc.x, 16); acc.x += __shfl_xor(acc.x, 32);
        acc.y += __shfl_xor(acc.y, 16); acc.y += __shfl_xor(acc.y, 32);
        acc.z += __shfl_xor(acc.z, 16); acc.z += __shfl_xor(acc.z, 32);
        acc.w += __shfl_xor(acc.w, 16); acc.w += __shfl_xor(acc.w, 32);
        if (lane < 16) {
            float inv = 1.f / l;
            float4 sk = *(const float4*)(s1 + (size_t)n * HC + s * 4);
            float4 o;
            o.x = acc.x * inv + sk.x;
            o.y = acc.y * inv + sk.y;
            o.z = acc.z * inv + sk.z;
            o.w = acc.w * inv + sk.w;
            o.x = o.x > 0.f ? o.x : expm1f(o.x);
            o.y = o.y > 0.f ? o.y : expm1f(o.y);
            o.z = o.z > 0.f ? o.z : expm1f(o.z);
            o.w = o.w > 0.f ? o.w : expm1f(o.w);
            *(float4*)(h + (size_t)n * HC + s * 4) = o;
        }
    } else if (lane < 16) {
        float4 sk = *(const float4*)(s1 + (size_t)n * HC + s * 4);
        float4 o;
        o.x = sk.x > 0.f ? sk.x : expm1f(sk.x);
        o.y = sk.y > 0.f ? sk.y : expm1f(sk.y);
        o.z = sk.z > 0.f ? sk.z : expm1f(sk.z);
        o.w = sk.w > 0.f ? sk.w : expm1f(sk.w);
        *(float4*)(h + (size_t)n * HC + s * 4) = o;
    }
}

// ---------------------------------------------------------------- layer2 node projections (64 -> 28), thread-per-node
__global__ __launch_bounds__(256) void proj2_kernel(
    const float* __restrict__ h,
    const float* __restrict__ Wq, const float* __restrict__ bq,
    const float* __restrict__ Wk, const float* __restrict__ bk,
    const float* __restrict__ Wv, const float* __restrict__ bv,
    const float* __restrict__ Ws, const float* __restrict__ bs,
    float* __restrict__ q2p, float* __restrict__ kv2, float* __restrict__ s2p)
{
    __shared__ float Wsm[HC][4][8];   // 8 KB
    __shared__ float Bsm[4][8];
    const int t = threadIdx.x;

    for (int j = t; j < HC * 28; j += 256) {
        int i = j / 28, r = j % 28, mtx = r / 7, c = r % 7;
        const float* W = (mtx == 0) ? Wq : (mtx == 1) ? Wk : (mtx == 2) ? Wv : Ws;
        Wsm[i][mtx][c] = W[i * OUTF + c];
    }
    for (int j = t; j < HC * 4; j += 256)          // zero the c=7 pad
        Wsm[j >> 2][j & 3][7] = 0.f;
    if (t < 32) {
        int mtx = t >> 3, c = t & 7;
        const float* B = (mtx == 0) ? bq : (mtx == 1) ? bk : (mtx == 2) ? bv : bs;
        Bsm[mtx][c] = (c < 7) ? B[c] : 0.f;
    }
    __syncthreads();

    int n = blockIdx.x * 256 + t;
    if (n >= N_NODES) return;

    float acc[4][8];
#pragma unroll
    for (int mtx = 0; mtx < 4; mtx++)
#pragma unroll
        for (int c = 0; c < 8; c++) acc[mtx][c] = Bsm[mtx][c];

    const float4* hp = (const float4*)(h + (size_t)n * HC);
#pragma unroll 4
    for (int i4 = 0; i4 < 16; i4++) {
        float4 hv = hp[i4];
        float hx[4] = { hv.x, hv.y, hv.z, hv.w };
#pragma unroll
        for (int e = 0; e < 4; e++) {
            int i = i4 * 4 + e;
#pragma unroll
            for (int mtx = 0; mtx < 4; mtx++) {
                float4 wa = *(const float4*)&Wsm[i][mtx][0];
                float4 wb = *(const float4*)&Wsm[i][mtx][4];
                acc[mtx][0] += hx[e] * wa.x; acc[mtx][1] += hx[e] * wa.y;
                acc[mtx][2] += hx[e] * wa.z; acc[mtx][3] += hx[e] * wa.w;
                acc[mtx][4] += hx[e] * wb.x; acc[mtx][5] += hx[e] * wb.y;
                acc[mtx][6] += hx[e] * wb.z; acc[mtx][7] += hx[e] * wb.w;
            }
        }
    }

    float4* q2v = (float4*)(q2p + (size_t)n * 8);
    q2v[0] = make_float4(acc[0][0], acc[0][1], acc[0][2], acc[0][3]);
    q2v[1] = make_float4(acc[0][4], acc[0][5], acc[0][6], acc[0][7]);
    float4* kvv = (float4*)(kv2 + (size_t)n * 16);
    kvv[0] = make_float4(acc[1][0], acc[1][1], acc[1][2], acc[1][3]);
    kvv[1] = make_float4(acc[1][4], acc[1][5], acc[1][6], acc[1][7]);
    kvv[2] = make_float4(acc[2][0], acc[2][1], acc[2][2], acc[2][3]);
    kvv[3] = make_float4(acc[2][4], acc[2][5], acc[2][6], acc[2][7]);
    float4* s2v = (float4*)(s2p + (size_t)n * 8);
    s2v[0] = make_float4(acc[3][0], acc[3][1], acc[3][2], acc[3][3]);
    s2v[1] = make_float4(acc[3][4], acc[3][5], acc[3][6], acc[3][7]);
}

// ---------------------------------------------------------------- layer2 attention: one wave per dst node
__global__ __launch_bounds__(256) void attn2_kernel(
    const int* __restrict__ offs, const float4* __restrict__ erec,
    const float* __restrict__ q2p, const float* __restrict__ kv2,
    const float* __restrict__ s2p, float* __restrict__ out)
{
    int n    = (blockIdx.x * 256 + threadIdx.x) >> 6;
    int lane = threadIdx.x & 63;
    if (n >= N_NODES) return;

    float4 qa = *(const float4*)(q2p + (size_t)n * 8);
    float4 qb = *(const float4*)(q2p + (size_t)n * 8 + 4);
    int beg = offs[n], end = offs[n + 1];

    float m = -3.402823466e38f, l = 0.f, a[OUTF];
#pragma unroll
    for (int c = 0; c < OUTF; c++) a[c] = 0.f;

    for (int i = beg + lane; i < end; i += 64) {
        int src = __float_as_int(erec[i].x);
        const float4* kvp = (const float4*)(kv2 + (size_t)src * 16);
        float4 ka = kvp[0], kb = kvp[1], va = kvp[2], vb = kvp[3];
        float dot = qa.x * ka.x + qa.y * ka.y + qa.z * ka.z + qa.w * ka.w
                  + qb.x * kb.x + qb.y * kb.y + qb.z * kb.z;
        float logit = dot * 0.37796447300922725f;       // 1/sqrt(7)
        float mn = fmaxf(m, logit);
        float sc = __expf(m - mn);
        float pe = __expf(logit - mn);
        l = l * sc + pe;
        a[0] = a[0] * sc + pe * va.x;
        a[1] = a[1] * sc + pe * va.y;
        a[2] = a[2] * sc + pe * va.z;
        a[3] = a[3] * sc + pe * va.w;
        a[4] = a[4] * sc + pe * vb.x;
        a[5] = a[5] * sc + pe * vb.y;
        a[6] = a[6] * sc + pe * vb.z;
        m = mn;
    }

    if (end > beg) {
        float M = dpp_max16(m);
        M = fmaxf(M, __shfl_xor(M, 16));
        M = fmaxf(M, __shfl_xor(M, 32));
        float sc = __expf(m - M);
        l *= sc;
#pragma unroll
        for (int c = 0; c < OUTF; c++) a[c] *= sc;
        l = dpp_add16(l); l += __shfl_xor(l, 16); l += __shfl_xor(l, 32);
#pragma unroll
        for (int c = 0; c < OUTF; c++) {
            float t = dpp_add16(a[c]);
            t += __shfl_xor(t, 16); t += __shfl_xor(t, 32);
            a[c] = t;
        }
        if (lane == 0) {
            float inv = 1.f / fmaxf(l, 1e-16f);
#pragma unroll
            for (int c = 0; c < OUTF; c++)
                out[(size_t)n * OUTF + c] = a[c] * inv + s2p[(size_t)n * 8 + c];
        }
    } else if (lane == 0) {
#pragma unroll
        for (int c = 0; c < OUTF; c++)
            out[(size_t)n * OUTF + c] = s2p[(size_t)n * 8 + c];
    }
}

// ----------------------------------------------------------------
extern "C" void kernel_launch(void* const* d_in, const int* in_sizes, int n_in,
                              void* d_out, int out_size, void* d_ws, size_t ws_size,
                              hipStream_t stream)
{
    const float* x    = (const float*)d_in[0];
    const float* ea   = (const float*)d_in[1];
    const int*   ei   = (const int*)d_in[2];
    const float* Wq1  = (const float*)d_in[3];
    const float* bq1  = (const float*)d_in[4];
    const float* Wk1  = (const float*)d_in[5];
    const float* bk1  = (const float*)d_in[6];
    const float* Wv1  = (const float*)d_in[7];
    const float* bv1  = (const float*)d_in[8];
    const float* We1  = (const float*)d_in[9];
    const float* Ws1  = (const float*)d_in[10];
    const float* bs1  = (const float*)d_in[11];
    const float* Wq2  = (const float*)d_in[12];
    const float* bq2  = (const float*)d_in[13];
    const float* Wk2  = (const float*)d_in[14];
    const float* bk2  = (const float*)d_in[15];
    const float* Wv2  = (const float*)d_in[16];
    const float* bv2  = (const float*)d_in[17];
    const float* Ws2  = (const float*)d_in[18];
    const float* bs2  = (const float*)d_in[19];
    float* out = (float*)d_out;

    // workspace layout (f32 words), ~84 MB total; all segments 16B-aligned.
    float* ws = (float*)d_ws;
    float*  q1   = ws;                               // N*64
    float*  k1   = q1 + (size_t)N_NODES * HC;
    float*  v1   = k1 + (size_t)N_NODES * HC;
    float*  s1   = v1 + (size_t)N_NODES * HC;
    float*  hbuf = q1;                               // alias: attn1 reads q1 row n then writes h row n
    float4* erec = (float4*)(s1 + (size_t)N_NODES * HC);    // E x 16B
    float*  q2p  = (float*)(erec + N_EDGES);         // N*8
    float*  kv2  = q2p + (size_t)N_NODES * 8;        // N*16
    float*  s2p  = kv2 + (size_t)N_NODES * 16;       // N*8
    int*    count  = (int*)(s2p + (size_t)N_NODES * 8);     // N
    int*    offs   = count + N_NODES;                // N+1
    int*    cursor = offs + N_NODES + 1;             // N
    int*    pre    = cursor + N_NODES;               // N
    int*    bsum   = pre + N_NODES;                  // NSB
    int*    bofs   = bsum + NSB;                     // NSB

    const int eb = (N_EDGES + 255) / 256;
    const int nwave_blocks = (N_NODES * 64 + 255) / 256;

    init_kernel<<<(N_NODES + 255) / 256, 256, 0, stream>>>(count);

    proj1_kernel<<<N_NODES / P1_NB, 64, 0, stream>>>(
        x, Wq1, bq1, Wk1, bk1, Wv1, bv1, Ws1, bs1, q1, k1, v1, s1);

    hist_kernel<<<eb, 256, 0, stream>>>(ei, count);
    scan1_kernel<<<NSB, 256, 0, stream>>>(count, pre, bsum);
    scan2_kernel<<<1, 256, 0, stream>>>(bsum, bofs);
    scan3_kernel<<<NSB, 256, 0, stream>>>(pre, bofs, offs, cursor);
    scatter_kernel<<<eb, 256, 0, stream>>>(ei, ea, cursor, erec);

    attn1_kernel<<<nwave_blocks, 256, 0, stream>>>(
        offs, erec, We1, q1, k1, v1, s1, hbuf);

    proj2_kernel<<<(N_NODES + 255) / 256, 256, 0, stream>>>(
        hbuf, Wq2, bq2, Wk2, bk2, Wv2, bv2, Ws2, bs2, q2p, kv2, s2p);

    attn2_kernel<<<nwave_blocks, 256, 0, stream>>>(
        offs, erec, q2p, kv2, s2p, out);
}

// Round 12
// 236.431 us; speedup vs baseline: 1.1963x; 1.1963x over previous
//
#include <hip/hip_runtime.h>

// TransformerClassification: 2-layer PyG TransformerConv GNN on MI355X.
// Round 12: proj1 reverted to round-7 exact inner loop (71us empirical best;
// r8/r9/r11 variants all regressed). hist fused into proj1's grid (rides on
// idle CUs). attn2: 4 nodes/wave x 16 lanes, DPP-only merge, coalesced erec.

#define N_NODES 50000
#define N_EDGES 800000
#define IN_F    128
#define HC      64      // heads*ch layer1
#define NH      4
#define CH      16
#define OUTF    7

#define NSB ((N_NODES + 255) / 256)   // 196 scan blocks
#define P1_NB 16
#define P1_BLOCKS (N_NODES / P1_NB)   // 3125
#define HIST_EPB 256
#define HIST_BLOCKS ((N_EDGES + HIST_EPB - 1) / HIST_EPB)  // 3125

// ---------------- DPP helpers ----------------
__device__ __forceinline__ float dpp_add16(float x) {
    int t;
    t = __builtin_amdgcn_update_dpp(0, __float_as_int(x), 0xB1, 0xF, 0xF, false);
    x += __int_as_float(t);
    t = __builtin_amdgcn_update_dpp(0, __float_as_int(x), 0x4E, 0xF, 0xF, false);
    x += __int_as_float(t);
    t = __builtin_amdgcn_update_dpp(0, __float_as_int(x), 0x124, 0xF, 0xF, false);
    x += __int_as_float(t);
    t = __builtin_amdgcn_update_dpp(0, __float_as_int(x), 0x128, 0xF, 0xF, false);
    x += __int_as_float(t);
    return x;
}
__device__ __forceinline__ float dpp_max16(float x) {
    int t;
    t = __builtin_amdgcn_update_dpp(0, __float_as_int(x), 0xB1, 0xF, 0xF, false);
    x = fmaxf(x, __int_as_float(t));
    t = __builtin_amdgcn_update_dpp(0, __float_as_int(x), 0x4E, 0xF, 0xF, false);
    x = fmaxf(x, __int_as_float(t));
    t = __builtin_amdgcn_update_dpp(0, __float_as_int(x), 0x124, 0xF, 0xF, false);
    x = fmaxf(x, __int_as_float(t));
    t = __builtin_amdgcn_update_dpp(0, __float_as_int(x), 0x128, 0xF, 0xF, false);
    x = fmaxf(x, __int_as_float(t));
    return x;
}
__device__ __forceinline__ float dpp_add4(float x) {
    int t;
    t = __builtin_amdgcn_update_dpp(0, __float_as_int(x), 0xB1, 0xF, 0xF, false);
    x += __int_as_float(t);
    t = __builtin_amdgcn_update_dpp(0, __float_as_int(x), 0x4E, 0xF, 0xF, false);
    x += __int_as_float(t);
    return x;
}

// ---------------------------------------------------------------- init: zero the histogram
__global__ __launch_bounds__(256) void init_kernel(int* __restrict__ count)
{
    int i = blockIdx.x * 256 + threadIdx.x;
    if (i < N_NODES) count[i] = 0;
}

// ---------------------------------------------------------------- layer1 projections + fused dst histogram
// blocks [0, P1_BLOCKS): round-7 proj1 (16 nodes, 64 threads, col per lane).
// blocks [P1_BLOCKS, +HIST_BLOCKS): 256-edge histogram chunks on idle CUs.
__global__ __launch_bounds__(64) void proj1_hist_kernel(
    const float* __restrict__ x,
    const float* __restrict__ Wq, const float* __restrict__ bq,
    const float* __restrict__ Wk, const float* __restrict__ bk,
    const float* __restrict__ Wv, const float* __restrict__ bv,
    const float* __restrict__ Ws, const float* __restrict__ bs,
    float* __restrict__ q1, float* __restrict__ k1,
    float* __restrict__ v1, float* __restrict__ s1,
    const int* __restrict__ ei, int* __restrict__ count)
{
    __shared__ float xs[P1_NB][IN_F];
    const int t = threadIdx.x;

    if (blockIdx.x >= P1_BLOCKS) {
        int e0 = (blockIdx.x - P1_BLOCKS) * HIST_EPB;
        int e1 = e0 + HIST_EPB < N_EDGES ? e0 + HIST_EPB : N_EDGES;
        for (int e = e0 + t; e < e1; e += 64)
            atomicAdd(count + ei[N_EDGES + e], 1);
        return;
    }

    const int n0 = blockIdx.x * P1_NB;
    for (int j = t; j < P1_NB * IN_F; j += 64)
        xs[j >> 7][j & 127] = x[(size_t)n0 * IN_F + j];
    __syncthreads();

    float aq[P1_NB], ak[P1_NB], av[P1_NB], as_[P1_NB];
#pragma unroll
    for (int n = 0; n < P1_NB; n++) { aq[n] = ak[n] = av[n] = as_[n] = 0.f; }

    for (int i = 0; i < IN_F; i++) {
        float wq = Wq[i * HC + t];
        float wk = Wk[i * HC + t];
        float wv = Wv[i * HC + t];
        float ws = Ws[i * HC + t];
#pragma unroll
        for (int n = 0; n < P1_NB; n++) {
            float xv = xs[n][i];
            aq[n] += xv * wq; ak[n] += xv * wk;
            av[n] += xv * wv; as_[n] += xv * ws;
        }
    }
    float bqv = bq[t], bkv = bk[t], bvv = bv[t], bsv = bs[t];
#pragma unroll
    for (int n = 0; n < P1_NB; n++) {
        size_t o = (size_t)(n0 + n) * HC + t;
        q1[o] = aq[n] + bqv; k1[o] = ak[n] + bkv;
        v1[o] = av[n] + bvv; s1[o] = as_[n] + bsv;
    }
}

// ---------------------------------------------------------------- scan phase 1
__global__ __launch_bounds__(256) void scan1_kernel(
    const int* __restrict__ count, int* __restrict__ pre, int* __restrict__ bsum)
{
    __shared__ int sdata[256];
    const int t = threadIdx.x;
    const int i = blockIdx.x * 256 + t;
    int v = (i < N_NODES) ? count[i] : 0;
    sdata[t] = v;
    __syncthreads();
    for (int d = 1; d < 256; d <<= 1) {
        int u = (t >= d) ? sdata[t - d] : 0;
        __syncthreads();
        sdata[t] += u;
        __syncthreads();
    }
    if (i < N_NODES) pre[i] = sdata[t] - v;
    if (t == 255) bsum[blockIdx.x] = sdata[255];
}

// ---------------------------------------------------------------- scan phase 2 (1 block)
__global__ __launch_bounds__(256) void scan2_kernel(
    int* __restrict__ bsum, int* __restrict__ bofs)
{
    __shared__ int sdata[256];
    const int t = threadIdx.x;
    int v = (t < NSB) ? bsum[t] : 0;
    sdata[t] = v;
    __syncthreads();
    for (int d = 1; d < 256; d <<= 1) {
        int u = (t >= d) ? sdata[t - d] : 0;
        __syncthreads();
        sdata[t] += u;
        __syncthreads();
    }
    if (t < NSB) bofs[t] = sdata[t] - v;
}

// ---------------------------------------------------------------- scan phase 3
__global__ __launch_bounds__(256) void scan3_kernel(
    const int* __restrict__ pre, const int* __restrict__ bofs,
    int* __restrict__ offs, int* __restrict__ cursor)
{
    const int i = blockIdx.x * 256 + threadIdx.x;
    if (i < N_NODES) {
        int o = pre[i] + bofs[i >> 8];
        offs[i] = o; cursor[i] = o;
    }
    if (i == 0) offs[N_NODES] = N_EDGES;
}

// ---------------------------------------------------------------- scatter: one packed 16B record per edge
__global__ __launch_bounds__(256) void scatter_kernel(
    const int* __restrict__ ei, const float* __restrict__ ea,
    int* __restrict__ cursor, float4* __restrict__ erec)
{
    int e = blockIdx.x * 256 + threadIdx.x;
    if (e >= N_EDGES) return;
    int dst = ei[N_EDGES + e];
    int pos = atomicAdd(cursor + dst, 1);
    float4 r;
    r.x = __int_as_float(ei[e]);
    r.y = ea[(size_t)e * 2];
    r.z = ea[(size_t)e * 2 + 1];
    r.w = 0.f;
    erec[pos] = r;
}

// ---------------------------------------------------------------- layer1 attention: one wave per dst node
// 4 edges per wave (g = lane>>4), 16 lanes per edge (s = lane&15 owns
// channels 4s..4s+3 as float4). Head dot = DPP quad sum.
__global__ __launch_bounds__(256) void attn1_kernel(
    const int* __restrict__ offs, const float4* __restrict__ erec,
    const float* __restrict__ We,
    const float* __restrict__ q1, const float* __restrict__ k1,
    const float* __restrict__ v1, const float* __restrict__ s1,
    float* __restrict__ h)
{
    int n    = (blockIdx.x * 256 + threadIdx.x) >> 6;
    int lane = threadIdx.x & 63;
    if (n >= N_NODES) return;
    const int g = lane >> 4;     // edge slot 0..3
    const int s = lane & 15;     // channel quad: channels 4s..4s+3

    const float4 qv  = *(const float4*)(q1 + (size_t)n * HC + s * 4);
    const float4 We0 = *(const float4*)(We + s * 4);
    const float4 We1 = *(const float4*)(We + HC + s * 4);
    const int beg = offs[n], end = offs[n + 1];

    float m = -3.402823466e38f, l = 0.f;
    float4 acc = make_float4(0.f, 0.f, 0.f, 0.f);

    for (int base = beg; base < end; base += 4) {
        int i = base + g;
        bool valid = (i < end);
        float4 r = erec[valid ? i : beg];
        int src = __float_as_int(r.x);
        size_t b = (size_t)src * HC + s * 4;
        float4 kk = *(const float4*)(k1 + b);
        float4 vv = *(const float4*)(v1 + b);
        float4 ec = make_float4(r.y * We0.x + r.z * We1.x,
                                r.y * We0.y + r.z * We1.y,
                                r.y * We0.z + r.z * We1.z,
                                r.y * We0.w + r.z * We1.w);
        float d = qv.x * (kk.x + ec.x) + qv.y * (kk.y + ec.y)
                + qv.z * (kk.z + ec.z) + qv.w * (kk.w + ec.w);
        d = dpp_add4(d);                          // head dot (16 channels)
        float logit = valid ? d * 0.25f : -3.402823466e38f;   // 1/sqrt(16)
        float mn = fmaxf(m, logit);
        float sm = __expf(m - mn);
        float pe = valid ? __expf(logit - mn) : 0.f;
        l = l * sm + pe;
        acc.x = acc.x * sm + pe * (vv.x + ec.x);
        acc.y = acc.y * sm + pe * (vv.y + ec.y);
        acc.z = acc.z * sm + pe * (vv.z + ec.z);
        acc.w = acc.w * sm + pe * (vv.w + ec.w);
        m = mn;
    }

    if (end > beg) {
        float M = fmaxf(m, __shfl_xor(m, 16));
        M = fmaxf(M, __shfl_xor(M, 32));
        float sc = __expf(m - M);                 // empty group: -inf -> 0
        l *= sc; acc.x *= sc; acc.y *= sc; acc.z *= sc; acc.w *= sc;
        l += __shfl_xor(l, 16);  l += __shfl_xor(l, 32);
        acc.x += __shfl_xor(acc.x, 16); acc.x += __shfl_xor(acc.x, 32);
        acc.y += __shfl_xor(acc.y, 16); acc.y += __shfl_xor(acc.y, 32);
        acc.z += __shfl_xor(acc.z, 16); acc.z += __shfl_xor(acc.z, 32);
        acc.w += __shfl_xor(acc.w, 16); acc.w += __shfl_xor(acc.w, 32);
        if (lane < 16) {
            float inv = 1.f / l;
            float4 sk = *(const float4*)(s1 + (size_t)n * HC + s * 4);
            float4 o;
            o.x = acc.x * inv + sk.x;
            o.y = acc.y * inv + sk.y;
            o.z = acc.z * inv + sk.z;
            o.w = acc.w * inv + sk.w;
            o.x = o.x > 0.f ? o.x : expm1f(o.x);
            o.y = o.y > 0.f ? o.y : expm1f(o.y);
            o.z = o.z > 0.f ? o.z : expm1f(o.z);
            o.w = o.w > 0.f ? o.w : expm1f(o.w);
            *(float4*)(h + (size_t)n * HC + s * 4) = o;
        }
    } else if (lane < 16) {
        float4 sk = *(const float4*)(s1 + (size_t)n * HC + s * 4);
        float4 o;
        o.x = sk.x > 0.f ? sk.x : expm1f(sk.x);
        o.y = sk.y > 0.f ? sk.y : expm1f(sk.y);
        o.z = sk.z > 0.f ? sk.z : expm1f(sk.z);
        o.w = sk.w > 0.f ? sk.w : expm1f(sk.w);
        *(float4*)(h + (size_t)n * HC + s * 4) = o;
    }
}

// ---------------------------------------------------------------- layer2 node projections (64 -> 28), thread-per-node
__global__ __launch_bounds__(256) void proj2_kernel(
    const float* __restrict__ h,
    const float* __restrict__ Wq, const float* __restrict__ bq,
    const float* __restrict__ Wk, const float* __restrict__ bk,
    const float* __restrict__ Wv, const float* __restrict__ bv,
    const float* __restrict__ Ws, const float* __restrict__ bs,
    float* __restrict__ q2p, float* __restrict__ kv2, float* __restrict__ s2p)
{
    __shared__ float Wsm[HC][4][8];   // 8 KB
    __shared__ float Bsm[4][8];
    const int t = threadIdx.x;

    for (int j = t; j < HC * 28; j += 256) {
        int i = j / 28, r = j % 28, mtx = r / 7, c = r % 7;
        const float* W = (mtx == 0) ? Wq : (mtx == 1) ? Wk : (mtx == 2) ? Wv : Ws;
        Wsm[i][mtx][c] = W[i * OUTF + c];
    }
    for (int j = t; j < HC * 4; j += 256)          // zero the c=7 pad
        Wsm[j >> 2][j & 3][7] = 0.f;
    if (t < 32) {
        int mtx = t >> 3, c = t & 7;
        const float* B = (mtx == 0) ? bq : (mtx == 1) ? bk : (mtx == 2) ? bv : bs;
        Bsm[mtx][c] = (c < 7) ? B[c] : 0.f;
    }
    __syncthreads();

    int n = blockIdx.x * 256 + t;
    if (n >= N_NODES) return;

    float acc[4][8];
#pragma unroll
    for (int mtx = 0; mtx < 4; mtx++)
#pragma unroll
        for (int c = 0; c < 8; c++) acc[mtx][c] = Bsm[mtx][c];

    const float4* hp = (const float4*)(h + (size_t)n * HC);
#pragma unroll 4
    for (int i4 = 0; i4 < 16; i4++) {
        float4 hv = hp[i4];
        float hx[4] = { hv.x, hv.y, hv.z, hv.w };
#pragma unroll
        for (int e = 0; e < 4; e++) {
            int i = i4 * 4 + e;
#pragma unroll
            for (int mtx = 0; mtx < 4; mtx++) {
                float4 wa = *(const float4*)&Wsm[i][mtx][0];
                float4 wb = *(const float4*)&Wsm[i][mtx][4];
                acc[mtx][0] += hx[e] * wa.x; acc[mtx][1] += hx[e] * wa.y;
                acc[mtx][2] += hx[e] * wa.z; acc[mtx][3] += hx[e] * wa.w;
                acc[mtx][4] += hx[e] * wb.x; acc[mtx][5] += hx[e] * wb.y;
                acc[mtx][6] += hx[e] * wb.z; acc[mtx][7] += hx[e] * wb.w;
            }
        }
    }

    float4* q2v = (float4*)(q2p + (size_t)n * 8);
    q2v[0] = make_float4(acc[0][0], acc[0][1], acc[0][2], acc[0][3]);
    q2v[1] = make_float4(acc[0][4], acc[0][5], acc[0][6], acc[0][7]);
    float4* kvv = (float4*)(kv2 + (size_t)n * 16);
    kvv[0] = make_float4(acc[1][0], acc[1][1], acc[1][2], acc[1][3]);
    kvv[1] = make_float4(acc[1][4], acc[1][5], acc[1][6], acc[1][7]);
    kvv[2] = make_float4(acc[2][0], acc[2][1], acc[2][2], acc[2][3]);
    kvv[3] = make_float4(acc[2][4], acc[2][5], acc[2][6], acc[2][7]);
    float4* s2v = (float4*)(s2p + (size_t)n * 8);
    s2v[0] = make_float4(acc[3][0], acc[3][1], acc[3][2], acc[3][3]);
    s2v[1] = make_float4(acc[3][4], acc[3][5], acc[3][6], acc[3][7]);
}

// ---------------------------------------------------------------- layer2 attention: 4 nodes/wave, 16 lanes/node
// lanes stride the node's edges by 16; erec reads coalesce to 256B per group;
// merge is DPP-only within the 16-lane row; group leader writes 7 outputs.
__global__ __launch_bounds__(256) void attn2_kernel(
    const int* __restrict__ offs, const float4* __restrict__ erec,
    const float* __restrict__ q2p, const float* __restrict__ kv2,
    const float* __restrict__ s2p, float* __restrict__ out)
{
    int idx = blockIdx.x * 256 + threadIdx.x;
    int n   = idx >> 4;
    int s   = idx & 15;
    if (n >= N_NODES) return;

    float4 qa = *(const float4*)(q2p + (size_t)n * 8);
    float4 qb = *(const float4*)(q2p + (size_t)n * 8 + 4);
    int beg = offs[n], end = offs[n + 1];

    float m = -3.402823466e38f, l = 0.f, a[OUTF];
#pragma unroll
    for (int c = 0; c < OUTF; c++) a[c] = 0.f;

    for (int i = beg + s; i < end; i += 16) {
        int src = __float_as_int(erec[i].x);
        const float4* kvp = (const float4*)(kv2 + (size_t)src * 16);
        float4 ka = kvp[0], kb = kvp[1], va = kvp[2], vb = kvp[3];
        float dot = qa.x * ka.x + qa.y * ka.y + qa.z * ka.z + qa.w * ka.w
                  + qb.x * kb.x + qb.y * kb.y + qb.z * kb.z;
        float logit = dot * 0.37796447300922725f;       // 1/sqrt(7)
        float mn = fmaxf(m, logit);
        float sc = __expf(m - mn);
        float pe = __expf(logit - mn);
        l = l * sc + pe;
        a[0] = a[0] * sc + pe * va.x;
        a[1] = a[1] * sc + pe * va.y;
        a[2] = a[2] * sc + pe * va.z;
        a[3] = a[3] * sc + pe * va.w;
        a[4] = a[4] * sc + pe * vb.x;
        a[5] = a[5] * sc + pe * vb.y;
        a[6] = a[6] * sc + pe * vb.z;
        m = mn;
    }

    if (end > beg) {
        float M = dpp_max16(m);                   // lanes past degree hold -inf
        float sc = __expf(m - M);                 // -inf lanes -> 0
        l *= sc;
#pragma unroll
        for (int c = 0; c < OUTF; c++) a[c] *= sc;
        l = dpp_add16(l);
#pragma unroll
        for (int c = 0; c < OUTF; c++) a[c] = dpp_add16(a[c]);
        if (s == 0) {
            float inv = 1.f / fmaxf(l, 1e-16f);
#pragma unroll
            for (int c = 0; c < OUTF; c++)
                out[(size_t)n * OUTF + c] = a[c] * inv + s2p[(size_t)n * 8 + c];
        }
    } else if (s == 0) {
#pragma unroll
        for (int c = 0; c < OUTF; c++)
            out[(size_t)n * OUTF + c] = s2p[(size_t)n * 8 + c];
    }
}

// ----------------------------------------------------------------
extern "C" void kernel_launch(void* const* d_in, const int* in_sizes, int n_in,
                              void* d_out, int out_size, void* d_ws, size_t ws_size,
                              hipStream_t stream)
{
    const float* x    = (const float*)d_in[0];
    const float* ea   = (const float*)d_in[1];
    const int*   ei   = (const int*)d_in[2];
    const float* Wq1  = (const float*)d_in[3];
    const float* bq1  = (const float*)d_in[4];
    const float* Wk1  = (const float*)d_in[5];
    const float* bk1  = (const float*)d_in[6];
    const float* Wv1  = (const float*)d_in[7];
    const float* bv1  = (const float*)d_in[8];
    const float* We1  = (const float*)d_in[9];
    const float* Ws1  = (const float*)d_in[10];
    const float* bs1  = (const float*)d_in[11];
    const float* Wq2  = (const float*)d_in[12];
    const float* bq2  = (const float*)d_in[13];
    const float* Wk2  = (const float*)d_in[14];
    const float* bk2  = (const float*)d_in[15];
    const float* Wv2  = (const float*)d_in[16];
    const float* bv2  = (const float*)d_in[17];
    const float* Ws2  = (const float*)d_in[18];
    const float* bs2  = (const float*)d_in[19];
    float* out = (float*)d_out;

    // workspace layout (f32 words), ~84 MB total; all segments 16B-aligned.
    float* ws = (float*)d_ws;
    float*  q1   = ws;                               // N*64
    float*  k1   = q1 + (size_t)N_NODES * HC;
    float*  v1   = k1 + (size_t)N_NODES * HC;
    float*  s1   = v1 + (size_t)N_NODES * HC;
    float*  hbuf = q1;                               // alias: attn1 reads q1 row n then writes h row n
    float4* erec = (float4*)(s1 + (size_t)N_NODES * HC);    // E x 16B
    float*  q2p  = (float*)(erec + N_EDGES);         // N*8
    float*  kv2  = q2p + (size_t)N_NODES * 8;        // N*16
    float*  s2p  = kv2 + (size_t)N_NODES * 16;       // N*8
    int*    count  = (int*)(s2p + (size_t)N_NODES * 8);     // N
    int*    offs   = count + N_NODES;                // N+1
    int*    cursor = offs + N_NODES + 1;             // N
    int*    pre    = cursor + N_NODES;               // N
    int*    bsum   = pre + N_NODES;                  // NSB
    int*    bofs   = bsum + NSB;                     // NSB

    const int eb = (N_EDGES + 255) / 256;
    const int nwave_blocks = (N_NODES * 64 + 255) / 256;

    init_kernel<<<(N_NODES + 255) / 256, 256, 0, stream>>>(count);

    proj1_hist_kernel<<<P1_BLOCKS + HIST_BLOCKS, 64, 0, stream>>>(
        x, Wq1, bq1, Wk1, bk1, Wv1, bv1, Ws1, bs1, q1, k1, v1, s1, ei, count);

    scan1_kernel<<<NSB, 256, 0, stream>>>(count, pre, bsum);
    scan2_kernel<<<1, 256, 0, stream>>>(bsum, bofs);
    scan3_kernel<<<NSB, 256, 0, stream>>>(pre, bofs, offs, cursor);
    scatter_kernel<<<eb, 256, 0, stream>>>(ei, ea, cursor, erec);

    attn1_kernel<<<nwave_blocks, 256, 0, stream>>>(
        offs, erec, We1, q1, k1, v1, s1, hbuf);

    proj2_kernel<<<(N_NODES + 255) / 256, 256, 0, stream>>>(
        hbuf, Wq2, bq2, Wk2, bk2, Wv2, bv2, Ws2, bs2, q2p, kv2, s2p);

    attn2_kernel<<<(N_NODES * 16 + 255) / 256, 256, 0, stream>>>(
        offs, erec, q2p, kv2, s2p, out);
}

// Round 13
// 230.528 us; speedup vs baseline: 1.2269x; 1.0256x over previous
//
#include <hip/hip_runtime.h>

// TransformerClassification: 2-layer PyG TransformerConv GNN on MI355X.
// Round 13: proj1 -> bf16 MFMA GEMM (16x16x32, 4 waves = 4 matrices/block,
// A in LDS bf16 stride-136, B^T (Wt[col][k]) preconverted bf16 in L2).
// Scalar-FMA proj1 family exhausted at 71-90us; MFMA floor is ~15us.
// hist unfused again (r12 fusion was neutral). Rest = r12 (236us).

#define N_NODES 50000
#define N_EDGES 800000
#define IN_F    128
#define HC      64      // heads*ch layer1
#define NH      4
#define CH      16
#define OUTF    7

#define NSB ((N_NODES + 255) / 256)   // 196 scan blocks

typedef __attribute__((ext_vector_type(8))) short bf16x8;
typedef __attribute__((ext_vector_type(4))) float f32x4;

__device__ __forceinline__ unsigned short f2bf(float f) {
    unsigned u = __float_as_uint(f);
    unsigned r = u + 0x7FFFu + ((u >> 16) & 1u);   // round-to-nearest-even
    return (unsigned short)(r >> 16);
}

// ---------------- DPP helpers ----------------
__device__ __forceinline__ float dpp_add16(float x) {
    int t;
    t = __builtin_amdgcn_update_dpp(0, __float_as_int(x), 0xB1, 0xF, 0xF, false);
    x += __int_as_float(t);
    t = __builtin_amdgcn_update_dpp(0, __float_as_int(x), 0x4E, 0xF, 0xF, false);
    x += __int_as_float(t);
    t = __builtin_amdgcn_update_dpp(0, __float_as_int(x), 0x124, 0xF, 0xF, false);
    x += __int_as_float(t);
    t = __builtin_amdgcn_update_dpp(0, __float_as_int(x), 0x128, 0xF, 0xF, false);
    x += __int_as_float(t);
    return x;
}
__device__ __forceinline__ float dpp_max16(float x) {
    int t;
    t = __builtin_amdgcn_update_dpp(0, __float_as_int(x), 0xB1, 0xF, 0xF, false);
    x = fmaxf(x, __int_as_float(t));
    t = __builtin_amdgcn_update_dpp(0, __float_as_int(x), 0x4E, 0xF, 0xF, false);
    x = fmaxf(x, __int_as_float(t));
    t = __builtin_amdgcn_update_dpp(0, __float_as_int(x), 0x124, 0xF, 0xF, false);
    x = fmaxf(x, __int_as_float(t));
    t = __builtin_amdgcn_update_dpp(0, __float_as_int(x), 0x128, 0xF, 0xF, false);
    x = fmaxf(x, __int_as_float(t));
    return x;
}
__device__ __forceinline__ float dpp_add4(float x) {
    int t;
    t = __builtin_amdgcn_update_dpp(0, __float_as_int(x), 0xB1, 0xF, 0xF, false);
    x += __int_as_float(t);
    t = __builtin_amdgcn_update_dpp(0, __float_as_int(x), 0x4E, 0xF, 0xF, false);
    x += __int_as_float(t);
    return x;
}

// ---------------------------------------------------------------- init: zero the histogram
__global__ __launch_bounds__(256) void init_kernel(int* __restrict__ count)
{
    int i = blockIdx.x * 256 + threadIdx.x;
    if (i < N_NODES) count[i] = 0;
}

// ---------------------------------------------------------------- convert W -> Wt[mtx][col][k] bf16
__global__ __launch_bounds__(256) void convert_w_kernel(
    const float* __restrict__ Wq, const float* __restrict__ Wk,
    const float* __restrict__ Wv, const float* __restrict__ Ws,
    unsigned short* __restrict__ Wt)
{
    int i = blockIdx.x * 256 + threadIdx.x;   // 4*64*128 = 32768
    if (i >= 4 * HC * IN_F) return;
    int m   = i >> 13;          // /8192
    int col = (i >> 7) & 63;
    int k   = i & 127;
    const float* W = (m == 0) ? Wq : (m == 1) ? Wk : (m == 2) ? Wv : Ws;
    Wt[i] = f2bf(W[k * HC + col]);
}

// ---------------------------------------------------------------- layer1 projections via MFMA
// 16 nodes x 256 cols per block; wave w = matrix w (64 cols = 4 n-tiles).
// A: x rows bf16 in LDS (stride 136 -> aligned b128 + 2-way-free banks).
// B: Wt global (L1/L2-hot). D layout: col=lane&15, row=(lane>>4)*4+reg.
__global__ __launch_bounds__(256) void proj1_mfma_kernel(
    const float* __restrict__ x, const unsigned short* __restrict__ Wt,
    const float* __restrict__ bq, const float* __restrict__ bk,
    const float* __restrict__ bv, const float* __restrict__ bs,
    float* __restrict__ q1, float* __restrict__ k1,
    float* __restrict__ v1, float* __restrict__ s1)
{
    __shared__ unsigned short xs[16][136];
    const int t = threadIdx.x;
    const int w = t >> 6, lane = t & 63;
    const int n0 = blockIdx.x * 16;
    const int col16 = lane & 15, kg = lane >> 4;

    // B-fragments: 4 k-chunks x 4 n-tiles, from global (shared across blocks)
    bf16x8 bfrag[4][4];
#pragma unroll
    for (int tt = 0; tt < 4; tt++) {
        const unsigned short* bp = Wt + ((size_t)(w * 64 + tt * 16 + col16) * IN_F) + 8 * kg;
#pragma unroll
        for (int kc = 0; kc < 4; kc++)
            bfrag[kc][tt] = *(const bf16x8*)(bp + kc * 32);
    }

    // stage this block's 16 x-rows as bf16 into LDS
    {
        int row = t >> 4, k8 = (t & 15) * 8;
        const float* xp = x + (size_t)(n0 + row) * IN_F + k8;
        float4 f0 = *(const float4*)xp;
        float4 f1 = *(const float4*)(xp + 4);
        uint4 pk;
        pk.x = f2bf(f0.x) | ((unsigned)f2bf(f0.y) << 16);
        pk.y = f2bf(f0.z) | ((unsigned)f2bf(f0.w) << 16);
        pk.z = f2bf(f1.x) | ((unsigned)f2bf(f1.y) << 16);
        pk.w = f2bf(f1.z) | ((unsigned)f2bf(f1.w) << 16);
        *(uint4*)&xs[row][k8] = pk;
    }
    __syncthreads();

    f32x4 acc[4] = { {0,0,0,0}, {0,0,0,0}, {0,0,0,0}, {0,0,0,0} };
#pragma unroll
    for (int kc = 0; kc < 4; kc++) {
        bf16x8 a = *(const bf16x8*)&xs[col16][kc * 32 + 8 * kg];
#pragma unroll
        for (int tt = 0; tt < 4; tt++)
            acc[tt] = __builtin_amdgcn_mfma_f32_16x16x32_bf16(a, bfrag[kc][tt], acc[tt], 0, 0, 0);
    }

    const float* Bm = (w == 0) ? bq : (w == 1) ? bk : (w == 2) ? bv : bs;
    float*       Om = (w == 0) ? q1 : (w == 1) ? k1 : (w == 2) ? v1 : s1;
#pragma unroll
    for (int tt = 0; tt < 4; tt++) {
        int col = tt * 16 + col16;
        float bias = Bm[col];
#pragma unroll
        for (int r = 0; r < 4; r++) {
            int node = n0 + kg * 4 + r;
            Om[(size_t)node * HC + col] = acc[tt][r] + bias;
        }
    }
}

// ---------------------------------------------------------------- histogram of dst
__global__ __launch_bounds__(256) void hist_kernel(
    const int* __restrict__ ei, int* __restrict__ count)
{
    int e = blockIdx.x * 256 + threadIdx.x;
    if (e < N_EDGES) atomicAdd(count + ei[N_EDGES + e], 1);
}

// ---------------------------------------------------------------- scan phase 1
__global__ __launch_bounds__(256) void scan1_kernel(
    const int* __restrict__ count, int* __restrict__ pre, int* __restrict__ bsum)
{
    __shared__ int sdata[256];
    const int t = threadIdx.x;
    const int i = blockIdx.x * 256 + t;
    int v = (i < N_NODES) ? count[i] : 0;
    sdata[t] = v;
    __syncthreads();
    for (int d = 1; d < 256; d <<= 1) {
        int u = (t >= d) ? sdata[t - d] : 0;
        __syncthreads();
        sdata[t] += u;
        __syncthreads();
    }
    if (i < N_NODES) pre[i] = sdata[t] - v;
    if (t == 255) bsum[blockIdx.x] = sdata[255];
}

// ---------------------------------------------------------------- scan phase 2 (1 block)
__global__ __launch_bounds__(256) void scan2_kernel(
    int* __restrict__ bsum, int* __restrict__ bofs)
{
    __shared__ int sdata[256];
    const int t = threadIdx.x;
    int v = (t < NSB) ? bsum[t] : 0;
    sdata[t] = v;
    __syncthreads();
    for (int d = 1; d < 256; d <<= 1) {
        int u = (t >= d) ? sdata[t - d] : 0;
        __syncthreads();
        sdata[t] += u;
        __syncthreads();
    }
    if (t < NSB) bofs[t] = sdata[t] - v;
}

// ---------------------------------------------------------------- scan phase 3
__global__ __launch_bounds__(256) void scan3_kernel(
    const int* __restrict__ pre, const int* __restrict__ bofs,
    int* __restrict__ offs, int* __restrict__ cursor)
{
    const int i = blockIdx.x * 256 + threadIdx.x;
    if (i < N_NODES) {
        int o = pre[i] + bofs[i >> 8];
        offs[i] = o; cursor[i] = o;
    }
    if (i == 0) offs[N_NODES] = N_EDGES;
}

// ---------------------------------------------------------------- scatter: one packed 16B record per edge
__global__ __launch_bounds__(256) void scatter_kernel(
    const int* __restrict__ ei, const float* __restrict__ ea,
    int* __restrict__ cursor, float4* __restrict__ erec)
{
    int e = blockIdx.x * 256 + threadIdx.x;
    if (e >= N_EDGES) return;
    int dst = ei[N_EDGES + e];
    int pos = atomicAdd(cursor + dst, 1);
    float4 r;
    r.x = __int_as_float(ei[e]);
    r.y = ea[(size_t)e * 2];
    r.z = ea[(size_t)e * 2 + 1];
    r.w = 0.f;
    erec[pos] = r;
}

// ---------------------------------------------------------------- layer1 attention: one wave per dst node
// 4 edges per wave (g = lane>>4), 16 lanes per edge (s = lane&15 owns
// channels 4s..4s+3 as float4). Head dot = DPP quad sum.
__global__ __launch_bounds__(256) void attn1_kernel(
    const int* __restrict__ offs, const float4* __restrict__ erec,
    const float* __restrict__ We,
    const float* __restrict__ q1, const float* __restrict__ k1,
    const float* __restrict__ v1, const float* __restrict__ s1,
    float* __restrict__ h)
{
    int n    = (blockIdx.x * 256 + threadIdx.x) >> 6;
    int lane = threadIdx.x & 63;
    if (n >= N_NODES) return;
    const int g = lane >> 4;     // edge slot 0..3
    const int s = lane & 15;     // channel quad: channels 4s..4s+3

    const float4 qv  = *(const float4*)(q1 + (size_t)n * HC + s * 4);
    const float4 We0 = *(const float4*)(We + s * 4);
    const float4 We1 = *(const float4*)(We + HC + s * 4);
    const int beg = offs[n], end = offs[n + 1];

    float m = -3.402823466e38f, l = 0.f;
    float4 acc = make_float4(0.f, 0.f, 0.f, 0.f);

    for (int base = beg; base < end; base += 4) {
        int i = base + g;
        bool valid = (i < end);
        float4 r = erec[valid ? i : beg];
        int src = __float_as_int(r.x);
        size_t b = (size_t)src * HC + s * 4;
        float4 kk = *(const float4*)(k1 + b);
        float4 vv = *(const float4*)(v1 + b);
        float4 ec = make_float4(r.y * We0.x + r.z * We1.x,
                                r.y * We0.y + r.z * We1.y,
                                r.y * We0.z + r.z * We1.z,
                                r.y * We0.w + r.z * We1.w);
        float d = qv.x * (kk.x + ec.x) + qv.y * (kk.y + ec.y)
                + qv.z * (kk.z + ec.z) + qv.w * (kk.w + ec.w);
        d = dpp_add4(d);                          // head dot (16 channels)
        float logit = valid ? d * 0.25f : -3.402823466e38f;   // 1/sqrt(16)
        float mn = fmaxf(m, logit);
        float sm = __expf(m - mn);
        float pe = valid ? __expf(logit - mn) : 0.f;
        l = l * sm + pe;
        acc.x = acc.x * sm + pe * (vv.x + ec.x);
        acc.y = acc.y * sm + pe * (vv.y + ec.y);
        acc.z = acc.z * sm + pe * (vv.z + ec.z);
        acc.w = acc.w * sm + pe * (vv.w + ec.w);
        m = mn;
    }

    if (end > beg) {
        float M = fmaxf(m, __shfl_xor(m, 16));
        M = fmaxf(M, __shfl_xor(M, 32));
        float sc = __expf(m - M);                 // empty group: -inf -> 0
        l *= sc; acc.x *= sc; acc.y *= sc; acc.z *= sc; acc.w *= sc;
        l += __shfl_xor(l, 16);  l += __shfl_xor(l, 32);
        acc.x += __shfl_xor(acc.x, 16); acc.x += __shfl_xor(acc.x, 32);
        acc.y += __shfl_xor(acc.y, 16); acc.y += __shfl_xor(acc.y, 32);
        acc.z += __shfl_xor(acc.z, 16); acc.z += __shfl_xor(acc.z, 32);
        acc.w += __shfl_xor(acc.w, 16); acc.w += __shfl_xor(acc.w, 32);
        if (lane < 16) {
            float inv = 1.f / l;
            float4 sk = *(const float4*)(s1 + (size_t)n * HC + s * 4);
            float4 o;
            o.x = acc.x * inv + sk.x;
            o.y = acc.y * inv + sk.y;
            o.z = acc.z * inv + sk.z;
            o.w = acc.w * inv + sk.w;
            o.x = o.x > 0.f ? o.x : expm1f(o.x);
            o.y = o.y > 0.f ? o.y : expm1f(o.y);
            o.z = o.z > 0.f ? o.z : expm1f(o.z);
            o.w = o.w > 0.f ? o.w : expm1f(o.w);
            *(float4*)(h + (size_t)n * HC + s * 4) = o;
        }
    } else if (lane < 16) {
        float4 sk = *(const float4*)(s1 + (size_t)n * HC + s * 4);
        float4 o;
        o.x = sk.x > 0.f ? sk.x : expm1f(sk.x);
        o.y = sk.y > 0.f ? sk.y : expm1f(sk.y);
        o.z = sk.z > 0.f ? sk.z : expm1f(sk.z);
        o.w = sk.w > 0.f ? sk.w : expm1f(sk.w);
        *(float4*)(h + (size_t)n * HC + s * 4) = o;
    }
}

// ---------------------------------------------------------------- layer2 node projections (64 -> 28), thread-per-node
__global__ __launch_bounds__(256) void proj2_kernel(
    const float* __restrict__ h,
    const float* __restrict__ Wq, const float* __restrict__ bq,
    const float* __restrict__ Wk, const float* __restrict__ bk,
    const float* __restrict__ Wv, const float* __restrict__ bv,
    const float* __restrict__ Ws, const float* __restrict__ bs,
    float* __restrict__ q2p, float* __restrict__ kv2, float* __restrict__ s2p)
{
    __shared__ float Wsm[HC][4][8];   // 8 KB
    __shared__ float Bsm[4][8];
    const int t = threadIdx.x;

    for (int j = t; j < HC * 28; j += 256) {
        int i = j / 28, r = j % 28, mtx = r / 7, c = r % 7;
        const float* W = (mtx == 0) ? Wq : (mtx == 1) ? Wk : (mtx == 2) ? Wv : Ws;
        Wsm[i][mtx][c] = W[i * OUTF + c];
    }
    for (int j = t; j < HC * 4; j += 256)          // zero the c=7 pad
        Wsm[j >> 2][j & 3][7] = 0.f;
    if (t < 32) {
        int mtx = t >> 3, c = t & 7;
        const float* B = (mtx == 0) ? bq : (mtx == 1) ? bk : (mtx == 2) ? bv : bs;
        Bsm[mtx][c] = (c < 7) ? B[c] : 0.f;
    }
    __syncthreads();

    int n = blockIdx.x * 256 + t;
    if (n >= N_NODES) return;

    float acc[4][8];
#pragma unroll
    for (int mtx = 0; mtx < 4; mtx++)
#pragma unroll
        for (int c = 0; c < 8; c++) acc[mtx][c] = Bsm[mtx][c];

    const float4* hp = (const float4*)(h + (size_t)n * HC);
#pragma unroll 4
    for (int i4 = 0; i4 < 16; i4++) {
        float4 hv = hp[i4];
        float hx[4] = { hv.x, hv.y, hv.z, hv.w };
#pragma unroll
        for (int e = 0; e < 4; e++) {
            int i = i4 * 4 + e;
#pragma unroll
            for (int mtx = 0; mtx < 4; mtx++) {
                float4 wa = *(const float4*)&Wsm[i][mtx][0];
                float4 wb = *(const float4*)&Wsm[i][mtx][4];
                acc[mtx][0] += hx[e] * wa.x; acc[mtx][1] += hx[e] * wa.y;
                acc[mtx][2] += hx[e] * wa.z; acc[mtx][3] += hx[e] * wa.w;
                acc[mtx][4] += hx[e] * wb.x; acc[mtx][5] += hx[e] * wb.y;
                acc[mtx][6] += hx[e] * wb.z; acc[mtx][7] += hx[e] * wb.w;
            }
        }
    }

    float4* q2v = (float4*)(q2p + (size_t)n * 8);
    q2v[0] = make_float4(acc[0][0], acc[0][1], acc[0][2], acc[0][3]);
    q2v[1] = make_float4(acc[0][4], acc[0][5], acc[0][6], acc[0][7]);
    float4* kvv = (float4*)(kv2 + (size_t)n * 16);
    kvv[0] = make_float4(acc[1][0], acc[1][1], acc[1][2], acc[1][3]);
    kvv[1] = make_float4(acc[1][4], acc[1][5], acc[1][6], acc[1][7]);
    kvv[2] = make_float4(acc[2][0], acc[2][1], acc[2][2], acc[2][3]);
    kvv[3] = make_float4(acc[2][4], acc[2][5], acc[2][6], acc[2][7]);
    float4* s2v = (float4*)(s2p + (size_t)n * 8);
    s2v[0] = make_float4(acc[3][0], acc[3][1], acc[3][2], acc[3][3]);
    s2v[1] = make_float4(acc[3][4], acc[3][5], acc[3][6], acc[3][7]);
}

// ---------------------------------------------------------------- layer2 attention: 4 nodes/wave, 16 lanes/node
__global__ __launch_bounds__(256) void attn2_kernel(
    const int* __restrict__ offs, const float4* __restrict__ erec,
    const float* __restrict__ q2p, const float* __restrict__ kv2,
    const float* __restrict__ s2p, float* __restrict__ out)
{
    int idx = blockIdx.x * 256 + threadIdx.x;
    int n   = idx >> 4;
    int s   = idx & 15;
    if (n >= N_NODES) return;

    float4 qa = *(const float4*)(q2p + (size_t)n * 8);
    float4 qb = *(const float4*)(q2p + (size_t)n * 8 + 4);
    int beg = offs[n], end = offs[n + 1];

    float m = -3.402823466e38f, l = 0.f, a[OUTF];
#pragma unroll
    for (int c = 0; c < OUTF; c++) a[c] = 0.f;

    for (int i = beg + s; i < end; i += 16) {
        int src = __float_as_int(erec[i].x);
        const float4* kvp = (const float4*)(kv2 + (size_t)src * 16);
        float4 ka = kvp[0], kb = kvp[1], va = kvp[2], vb = kvp[3];
        float dot = qa.x * ka.x + qa.y * ka.y + qa.z * ka.z + qa.w * ka.w
                  + qb.x * kb.x + qb.y * kb.y + qb.z * kb.z;
        float logit = dot * 0.37796447300922725f;       // 1/sqrt(7)
        float mn = fmaxf(m, logit);
        float sc = __expf(m - mn);
        float pe = __expf(logit - mn);
        l = l * sc + pe;
        a[0] = a[0] * sc + pe * va.x;
        a[1] = a[1] * sc + pe * va.y;
        a[2] = a[2] * sc + pe * va.z;
        a[3] = a[3] * sc + pe * va.w;
        a[4] = a[4] * sc + pe * vb.x;
        a[5] = a[5] * sc + pe * vb.y;
        a[6] = a[6] * sc + pe * vb.z;
        m = mn;
    }

    if (end > beg) {
        float M = dpp_max16(m);                   // lanes past degree hold -inf
        float sc = __expf(m - M);                 // -inf lanes -> 0
        l *= sc;
#pragma unroll
        for (int c = 0; c < OUTF; c++) a[c] *= sc;
        l = dpp_add16(l);
#pragma unroll
        for (int c = 0; c < OUTF; c++) a[c] = dpp_add16(a[c]);
        if (s == 0) {
            float inv = 1.f / fmaxf(l, 1e-16f);
#pragma unroll
            for (int c = 0; c < OUTF; c++)
                out[(size_t)n * OUTF + c] = a[c] * inv + s2p[(size_t)n * 8 + c];
        }
    } else if (s == 0) {
#pragma unroll
        for (int c = 0; c < OUTF; c++)
            out[(size_t)n * OUTF + c] = s2p[(size_t)n * 8 + c];
    }
}

// ----------------------------------------------------------------
extern "C" void kernel_launch(void* const* d_in, const int* in_sizes, int n_in,
                              void* d_out, int out_size, void* d_ws, size_t ws_size,
                              hipStream_t stream)
{
    const float* x    = (const float*)d_in[0];
    const float* ea   = (const float*)d_in[1];
    const int*   ei   = (const int*)d_in[2];
    const float* Wq1  = (const float*)d_in[3];
    const float* bq1  = (const float*)d_in[4];
    const float* Wk1  = (const float*)d_in[5];
    const float* bk1  = (const float*)d_in[6];
    const float* Wv1  = (const float*)d_in[7];
    const float* bv1  = (const float*)d_in[8];
    const float* We1  = (const float*)d_in[9];
    const float* Ws1  = (const float*)d_in[10];
    const float* bs1  = (const float*)d_in[11];
    const float* Wq2  = (const float*)d_in[12];
    const float* bq2  = (const float*)d_in[13];
    const float* Wk2  = (const float*)d_in[14];
    const float* bk2  = (const float*)d_in[15];
    const float* Wv2  = (const float*)d_in[16];
    const float* bv2  = (const float*)d_in[17];
    const float* Ws2  = (const float*)d_in[18];
    const float* bs2  = (const float*)d_in[19];
    float* out = (float*)d_out;

    // workspace layout (f32 words), ~84 MB total; all segments 16B-aligned.
    float* ws = (float*)d_ws;
    float*  q1   = ws;                               // N*64
    float*  k1   = q1 + (size_t)N_NODES * HC;
    float*  v1   = k1 + (size_t)N_NODES * HC;
    float*  s1   = v1 + (size_t)N_NODES * HC;
    float*  hbuf = q1;                               // alias: attn1 reads q1 row n then writes h row n
    float4* erec = (float4*)(s1 + (size_t)N_NODES * HC);    // E x 16B
    float*  q2p  = (float*)(erec + N_EDGES);         // N*8
    float*  kv2  = q2p + (size_t)N_NODES * 8;        // N*16
    float*  s2p  = kv2 + (size_t)N_NODES * 16;       // N*8
    unsigned short* Wt = (unsigned short*)(s2p + (size_t)N_NODES * 8);  // 4*64*128 bf16 = 64KB
    int*    count  = (int*)(Wt + 4 * HC * IN_F);     // N
    int*    offs   = count + N_NODES;                // N+1
    int*    cursor = offs + N_NODES + 1;             // N
    int*    pre    = cursor + N_NODES;               // N
    int*    bsum   = pre + N_NODES;                  // NSB
    int*    bofs   = bsum + NSB;                     // NSB

    const int eb = (N_EDGES + 255) / 256;
    const int nwave_blocks = (N_NODES * 64 + 255) / 256;

    init_kernel<<<(N_NODES + 255) / 256, 256, 0, stream>>>(count);
    convert_w_kernel<<<(4 * HC * IN_F + 255) / 256, 256, 0, stream>>>(
        Wq1, Wk1, Wv1, Ws1, Wt);
    hist_kernel<<<eb, 256, 0, stream>>>(ei, count);

    proj1_mfma_kernel<<<N_NODES / 16, 256, 0, stream>>>(
        x, Wt, bq1, bk1, bv1, bs1, q1, k1, v1, s1);

    scan1_kernel<<<NSB, 256, 0, stream>>>(count, pre, bsum);
    scan2_kernel<<<1, 256, 0, stream>>>(bsum, bofs);
    scan3_kernel<<<NSB, 256, 0, stream>>>(pre, bofs, offs, cursor);
    scatter_kernel<<<eb, 256, 0, stream>>>(ei, ea, cursor, erec);

    attn1_kernel<<<nwave_blocks, 256, 0, stream>>>(
        offs, erec, We1, q1, k1, v1, s1, hbuf);

    proj2_kernel<<<(N_NODES + 255) / 256, 256, 0, stream>>>(
        hbuf, Wq2, bq2, Wk2, bk2, Wv2, bv2, Ws2, bs2, q2p, kv2, s2p);

    attn2_kernel<<<(N_NODES * 16 + 255) / 256, 256, 0, stream>>>(
        offs, erec, q2p, kv2, s2p, out);
}

// Round 14
// 214.571 us; speedup vs baseline: 1.3181x; 1.0744x over previous
//
#include <hip/hip_runtime.h>

// TransformerClassification: 2-layer PyG TransformerConv GNN on MI355X.
// Round 14: attn1 gather payload -> bf16. k1/v1 merged into kv1[node][128]
// bf16 (k cols 0..63, v cols 64..127): halves the 410MB/dispatch edge-gather
// demand that made attn1 (64us) memory-bound. MFMA epilogue writes bf16
// directly. Rest identical to round-13 (230us).

#define N_NODES 50000
#define N_EDGES 800000
#define IN_F    128
#define HC      64      // heads*ch layer1
#define NH      4
#define CH      16
#define OUTF    7

#define NSB ((N_NODES + 255) / 256)   // 196 scan blocks

typedef __attribute__((ext_vector_type(8))) short bf16x8;
typedef __attribute__((ext_vector_type(4))) float f32x4;

__device__ __forceinline__ unsigned short f2bf(float f) {
    unsigned u = __float_as_uint(f);
    unsigned r = u + 0x7FFFu + ((u >> 16) & 1u);   // round-to-nearest-even
    return (unsigned short)(r >> 16);
}
__device__ __forceinline__ float bflo(unsigned u) { return __uint_as_float(u << 16); }
__device__ __forceinline__ float bfhi(unsigned u) { return __uint_as_float(u & 0xFFFF0000u); }

// ---------------- DPP helpers ----------------
__device__ __forceinline__ float dpp_add16(float x) {
    int t;
    t = __builtin_amdgcn_update_dpp(0, __float_as_int(x), 0xB1, 0xF, 0xF, false);
    x += __int_as_float(t);
    t = __builtin_amdgcn_update_dpp(0, __float_as_int(x), 0x4E, 0xF, 0xF, false);
    x += __int_as_float(t);
    t = __builtin_amdgcn_update_dpp(0, __float_as_int(x), 0x124, 0xF, 0xF, false);
    x += __int_as_float(t);
    t = __builtin_amdgcn_update_dpp(0, __float_as_int(x), 0x128, 0xF, 0xF, false);
    x += __int_as_float(t);
    return x;
}
__device__ __forceinline__ float dpp_max16(float x) {
    int t;
    t = __builtin_amdgcn_update_dpp(0, __float_as_int(x), 0xB1, 0xF, 0xF, false);
    x = fmaxf(x, __int_as_float(t));
    t = __builtin_amdgcn_update_dpp(0, __float_as_int(x), 0x4E, 0xF, 0xF, false);
    x = fmaxf(x, __int_as_float(t));
    t = __builtin_amdgcn_update_dpp(0, __float_as_int(x), 0x124, 0xF, 0xF, false);
    x = fmaxf(x, __int_as_float(t));
    t = __builtin_amdgcn_update_dpp(0, __float_as_int(x), 0x128, 0xF, 0xF, false);
    x = fmaxf(x, __int_as_float(t));
    return x;
}
__device__ __forceinline__ float dpp_add4(float x) {
    int t;
    t = __builtin_amdgcn_update_dpp(0, __float_as_int(x), 0xB1, 0xF, 0xF, false);
    x += __int_as_float(t);
    t = __builtin_amdgcn_update_dpp(0, __float_as_int(x), 0x4E, 0xF, 0xF, false);
    x += __int_as_float(t);
    return x;
}

// ---------------------------------------------------------------- init: zero the histogram
__global__ __launch_bounds__(256) void init_kernel(int* __restrict__ count)
{
    int i = blockIdx.x * 256 + threadIdx.x;
    if (i < N_NODES) count[i] = 0;
}

// ---------------------------------------------------------------- convert W -> Wt[mtx][col][k] bf16
__global__ __launch_bounds__(256) void convert_w_kernel(
    const float* __restrict__ Wq, const float* __restrict__ Wk,
    const float* __restrict__ Wv, const float* __restrict__ Ws,
    unsigned short* __restrict__ Wt)
{
    int i = blockIdx.x * 256 + threadIdx.x;   // 4*64*128 = 32768
    if (i >= 4 * HC * IN_F) return;
    int m   = i >> 13;          // /8192
    int col = (i >> 7) & 63;
    int k   = i & 127;
    const float* W = (m == 0) ? Wq : (m == 1) ? Wk : (m == 2) ? Wv : Ws;
    Wt[i] = f2bf(W[k * HC + col]);
}

// ---------------------------------------------------------------- layer1 projections via MFMA
// 16 nodes x 256 cols per block; wave w = matrix w. q,s -> f32; k,v -> kv1 bf16.
__global__ __launch_bounds__(256) void proj1_mfma_kernel(
    const float* __restrict__ x, const unsigned short* __restrict__ Wt,
    const float* __restrict__ bq, const float* __restrict__ bk,
    const float* __restrict__ bv, const float* __restrict__ bs,
    float* __restrict__ q1, unsigned short* __restrict__ kv1,
    float* __restrict__ s1)
{
    __shared__ unsigned short xs[16][136];
    const int t = threadIdx.x;
    const int w = t >> 6, lane = t & 63;
    const int n0 = blockIdx.x * 16;
    const int col16 = lane & 15, kg = lane >> 4;

    // B-fragments: 4 k-chunks x 4 n-tiles, from global (shared across blocks)
    bf16x8 bfrag[4][4];
#pragma unroll
    for (int tt = 0; tt < 4; tt++) {
        const unsigned short* bp = Wt + ((size_t)(w * 64 + tt * 16 + col16) * IN_F) + 8 * kg;
#pragma unroll
        for (int kc = 0; kc < 4; kc++)
            bfrag[kc][tt] = *(const bf16x8*)(bp + kc * 32);
    }

    // stage this block's 16 x-rows as bf16 into LDS
    {
        int row = t >> 4, k8 = (t & 15) * 8;
        const float* xp = x + (size_t)(n0 + row) * IN_F + k8;
        float4 f0 = *(const float4*)xp;
        float4 f1 = *(const float4*)(xp + 4);
        uint4 pk;
        pk.x = f2bf(f0.x) | ((unsigned)f2bf(f0.y) << 16);
        pk.y = f2bf(f0.z) | ((unsigned)f2bf(f0.w) << 16);
        pk.z = f2bf(f1.x) | ((unsigned)f2bf(f1.y) << 16);
        pk.w = f2bf(f1.z) | ((unsigned)f2bf(f1.w) << 16);
        *(uint4*)&xs[row][k8] = pk;
    }
    __syncthreads();

    f32x4 acc[4] = { {0,0,0,0}, {0,0,0,0}, {0,0,0,0}, {0,0,0,0} };
#pragma unroll
    for (int kc = 0; kc < 4; kc++) {
        bf16x8 a = *(const bf16x8*)&xs[col16][kc * 32 + 8 * kg];
#pragma unroll
        for (int tt = 0; tt < 4; tt++)
            acc[tt] = __builtin_amdgcn_mfma_f32_16x16x32_bf16(a, bfrag[kc][tt], acc[tt], 0, 0, 0);
    }

    if (w == 0 || w == 3) {
        const float* Bm = (w == 0) ? bq : bs;
        float*       Om = (w == 0) ? q1 : s1;
#pragma unroll
        for (int tt = 0; tt < 4; tt++) {
            int col = tt * 16 + col16;
            float bias = Bm[col];
#pragma unroll
            for (int r = 0; r < 4; r++) {
                int node = n0 + kg * 4 + r;
                Om[(size_t)node * HC + col] = acc[tt][r] + bias;
            }
        }
    } else {
        const float* Bm = (w == 1) ? bk : bv;
        const int cbase = (w == 1) ? 0 : 64;
#pragma unroll
        for (int tt = 0; tt < 4; tt++) {
            int col = tt * 16 + col16;
            float bias = Bm[col];
#pragma unroll
            for (int r = 0; r < 4; r++) {
                int node = n0 + kg * 4 + r;
                kv1[(size_t)node * 128 + cbase + col] = f2bf(acc[tt][r] + bias);
            }
        }
    }
}

// ---------------------------------------------------------------- histogram of dst
__global__ __launch_bounds__(256) void hist_kernel(
    const int* __restrict__ ei, int* __restrict__ count)
{
    int e = blockIdx.x * 256 + threadIdx.x;
    if (e < N_EDGES) atomicAdd(count + ei[N_EDGES + e], 1);
}

// ---------------------------------------------------------------- scan phase 1
__global__ __launch_bounds__(256) void scan1_kernel(
    const int* __restrict__ count, int* __restrict__ pre, int* __restrict__ bsum)
{
    __shared__ int sdata[256];
    const int t = threadIdx.x;
    const int i = blockIdx.x * 256 + t;
    int v = (i < N_NODES) ? count[i] : 0;
    sdata[t] = v;
    __syncthreads();
    for (int d = 1; d < 256; d <<= 1) {
        int u = (t >= d) ? sdata[t - d] : 0;
        __syncthreads();
        sdata[t] += u;
        __syncthreads();
    }
    if (i < N_NODES) pre[i] = sdata[t] - v;
    if (t == 255) bsum[blockIdx.x] = sdata[255];
}

// ---------------------------------------------------------------- scan phase 2 (1 block)
__global__ __launch_bounds__(256) void scan2_kernel(
    int* __restrict__ bsum, int* __restrict__ bofs)
{
    __shared__ int sdata[256];
    const int t = threadIdx.x;
    int v = (t < NSB) ? bsum[t] : 0;
    sdata[t] = v;
    __syncthreads();
    for (int d = 1; d < 256; d <<= 1) {
        int u = (t >= d) ? sdata[t - d] : 0;
        __syncthreads();
        sdata[t] += u;
        __syncthreads();
    }
    if (t < NSB) bofs[t] = sdata[t] - v;
}

// ---------------------------------------------------------------- scan phase 3
__global__ __launch_bounds__(256) void scan3_kernel(
    const int* __restrict__ pre, const int* __restrict__ bofs,
    int* __restrict__ offs, int* __restrict__ cursor)
{
    const int i = blockIdx.x * 256 + threadIdx.x;
    if (i < N_NODES) {
        int o = pre[i] + bofs[i >> 8];
        offs[i] = o; cursor[i] = o;
    }
    if (i == 0) offs[N_NODES] = N_EDGES;
}

// ---------------------------------------------------------------- scatter: one packed 16B record per edge
__global__ __launch_bounds__(256) void scatter_kernel(
    const int* __restrict__ ei, const float* __restrict__ ea,
    int* __restrict__ cursor, float4* __restrict__ erec)
{
    int e = blockIdx.x * 256 + threadIdx.x;
    if (e >= N_EDGES) return;
    int dst = ei[N_EDGES + e];
    int pos = atomicAdd(cursor + dst, 1);
    float4 r;
    r.x = __int_as_float(ei[e]);
    r.y = ea[(size_t)e * 2];
    r.z = ea[(size_t)e * 2 + 1];
    r.w = 0.f;
    erec[pos] = r;
}

// ---------------------------------------------------------------- layer1 attention: one wave per dst node
// 4 edges/wave (g), 16 lanes/edge (s owns channels 4s..4s+3).
// kv1 gather is bf16: 8B k + 8B v per lane per edge (halved bytes).
__global__ __launch_bounds__(256) void attn1_kernel(
    const int* __restrict__ offs, const float4* __restrict__ erec,
    const float* __restrict__ We,
    const float* __restrict__ q1, const unsigned short* __restrict__ kv1,
    const float* __restrict__ s1, float* __restrict__ h)
{
    int n    = (blockIdx.x * 256 + threadIdx.x) >> 6;
    int lane = threadIdx.x & 63;
    if (n >= N_NODES) return;
    const int g = lane >> 4;     // edge slot 0..3
    const int s = lane & 15;     // channel quad: channels 4s..4s+3

    const float4 qv  = *(const float4*)(q1 + (size_t)n * HC + s * 4);
    const float4 We0 = *(const float4*)(We + s * 4);
    const float4 We1 = *(const float4*)(We + HC + s * 4);
    const int beg = offs[n], end = offs[n + 1];

    float m = -3.402823466e38f, l = 0.f;
    float4 acc = make_float4(0.f, 0.f, 0.f, 0.f);

    for (int base = beg; base < end; base += 4) {
        int i = base + g;
        bool valid = (i < end);
        float4 r = erec[valid ? i : beg];
        int src = __float_as_int(r.x);
        const unsigned short* kvp = kv1 + ((size_t)src << 7) + (s << 2);
        uint2 kraw = *(const uint2*)kvp;
        uint2 vraw = *(const uint2*)(kvp + 64);
        float k0 = bflo(kraw.x), k1 = bfhi(kraw.x);
        float k2 = bflo(kraw.y), k3 = bfhi(kraw.y);
        float v0 = bflo(vraw.x), v1 = bfhi(vraw.x);
        float v2 = bflo(vraw.y), v3 = bfhi(vraw.y);
        float4 ec = make_float4(r.y * We0.x + r.z * We1.x,
                                r.y * We0.y + r.z * We1.y,
                                r.y * We0.z + r.z * We1.z,
                                r.y * We0.w + r.z * We1.w);
        float d = qv.x * (k0 + ec.x) + qv.y * (k1 + ec.y)
                + qv.z * (k2 + ec.z) + qv.w * (k3 + ec.w);
        d = dpp_add4(d);                          // head dot (16 channels)
        float logit = valid ? d * 0.25f : -3.402823466e38f;   // 1/sqrt(16)
        float mn = fmaxf(m, logit);
        float sm = __expf(m - mn);
        float pe = valid ? __expf(logit - mn) : 0.f;
        l = l * sm + pe;
        acc.x = acc.x * sm + pe * (v0 + ec.x);
        acc.y = acc.y * sm + pe * (v1 + ec.y);
        acc.z = acc.z * sm + pe * (v2 + ec.z);
        acc.w = acc.w * sm + pe * (v3 + ec.w);
        m = mn;
    }

    if (end > beg) {
        float M = fmaxf(m, __shfl_xor(m, 16));
        M = fmaxf(M, __shfl_xor(M, 32));
        float sc = __expf(m - M);                 // empty group: -inf -> 0
        l *= sc; acc.x *= sc; acc.y *= sc; acc.z *= sc; acc.w *= sc;
        l += __shfl_xor(l, 16);  l += __shfl_xor(l, 32);
        acc.x += __shfl_xor(acc.x, 16); acc.x += __shfl_xor(acc.x, 32);
        acc.y += __shfl_xor(acc.y, 16); acc.y += __shfl_xor(acc.y, 32);
        acc.z += __shfl_xor(acc.z, 16); acc.z += __shfl_xor(acc.z, 32);
        acc.w += __shfl_xor(acc.w, 16); acc.w += __shfl_xor(acc.w, 32);
        if (lane < 16) {
            float inv = 1.f / l;
            float4 sk = *(const float4*)(s1 + (size_t)n * HC + s * 4);
            float4 o;
            o.x = acc.x * inv + sk.x;
            o.y = acc.y * inv + sk.y;
            o.z = acc.z * inv + sk.z;
            o.w = acc.w * inv + sk.w;
            o.x = o.x > 0.f ? o.x : expm1f(o.x);
            o.y = o.y > 0.f ? o.y : expm1f(o.y);
            o.z = o.z > 0.f ? o.z : expm1f(o.z);
            o.w = o.w > 0.f ? o.w : expm1f(o.w);
            *(float4*)(h + (size_t)n * HC + s * 4) = o;
        }
    } else if (lane < 16) {
        float4 sk = *(const float4*)(s1 + (size_t)n * HC + s * 4);
        float4 o;
        o.x = sk.x > 0.f ? sk.x : expm1f(sk.x);
        o.y = sk.y > 0.f ? sk.y : expm1f(sk.y);
        o.z = sk.z > 0.f ? sk.z : expm1f(sk.z);
        o.w = sk.w > 0.f ? sk.w : expm1f(sk.w);
        *(float4*)(h + (size_t)n * HC + s * 4) = o;
    }
}

// ---------------------------------------------------------------- layer2 node projections (64 -> 28), thread-per-node
__global__ __launch_bounds__(256) void proj2_kernel(
    const float* __restrict__ h,
    const float* __restrict__ Wq, const float* __restrict__ bq,
    const float* __restrict__ Wk, const float* __restrict__ bk,
    const float* __restrict__ Wv, const float* __restrict__ bv,
    const float* __restrict__ Ws, const float* __restrict__ bs,
    float* __restrict__ q2p, float* __restrict__ kv2, float* __restrict__ s2p)
{
    __shared__ float Wsm[HC][4][8];   // 8 KB
    __shared__ float Bsm[4][8];
    const int t = threadIdx.x;

    for (int j = t; j < HC * 28; j += 256) {
        int i = j / 28, r = j % 28, mtx = r / 7, c = r % 7;
        const float* W = (mtx == 0) ? Wq : (mtx == 1) ? Wk : (mtx == 2) ? Wv : Ws;
        Wsm[i][mtx][c] = W[i * OUTF + c];
    }
    for (int j = t; j < HC * 4; j += 256)          // zero the c=7 pad
        Wsm[j >> 2][j & 3][7] = 0.f;
    if (t < 32) {
        int mtx = t >> 3, c = t & 7;
        const float* B = (mtx == 0) ? bq : (mtx == 1) ? bk : (mtx == 2) ? bv : bs;
        Bsm[mtx][c] = (c < 7) ? B[c] : 0.f;
    }
    __syncthreads();

    int n = blockIdx.x * 256 + t;
    if (n >= N_NODES) return;

    float acc[4][8];
#pragma unroll
    for (int mtx = 0; mtx < 4; mtx++)
#pragma unroll
        for (int c = 0; c < 8; c++) acc[mtx][c] = Bsm[mtx][c];

    const float4* hp = (const float4*)(h + (size_t)n * HC);
#pragma unroll 4
    for (int i4 = 0; i4 < 16; i4++) {
        float4 hv = hp[i4];
        float hx[4] = { hv.x, hv.y, hv.z, hv.w };
#pragma unroll
        for (int e = 0; e < 4; e++) {
            int i = i4 * 4 + e;
#pragma unroll
            for (int mtx = 0; mtx < 4; mtx++) {
                float4 wa = *(const float4*)&Wsm[i][mtx][0];
                float4 wb = *(const float4*)&Wsm[i][mtx][4];
                acc[mtx][0] += hx[e] * wa.x; acc[mtx][1] += hx[e] * wa.y;
                acc[mtx][2] += hx[e] * wa.z; acc[mtx][3] += hx[e] * wa.w;
                acc[mtx][4] += hx[e] * wb.x; acc[mtx][5] += hx[e] * wb.y;
                acc[mtx][6] += hx[e] * wb.z; acc[mtx][7] += hx[e] * wb.w;
            }
        }
    }

    float4* q2v = (float4*)(q2p + (size_t)n * 8);
    q2v[0] = make_float4(acc[0][0], acc[0][1], acc[0][2], acc[0][3]);
    q2v[1] = make_float4(acc[0][4], acc[0][5], acc[0][6], acc[0][7]);
    float4* kvv = (float4*)(kv2 + (size_t)n * 16);
    kvv[0] = make_float4(acc[1][0], acc[1][1], acc[1][2], acc[1][3]);
    kvv[1] = make_float4(acc[1][4], acc[1][5], acc[1][6], acc[1][7]);
    kvv[2] = make_float4(acc[2][0], acc[2][1], acc[2][2], acc[2][3]);
    kvv[3] = make_float4(acc[2][4], acc[2][5], acc[2][6], acc[2][7]);
    float4* s2v = (float4*)(s2p + (size_t)n * 8);
    s2v[0] = make_float4(acc[3][0], acc[3][1], acc[3][2], acc[3][3]);
    s2v[1] = make_float4(acc[3][4], acc[3][5], acc[3][6], acc[3][7]);
}

// ---------------------------------------------------------------- layer2 attention: 4 nodes/wave, 16 lanes/node
__global__ __launch_bounds__(256) void attn2_kernel(
    const int* __restrict__ offs, const float4* __restrict__ erec,
    const float* __restrict__ q2p, const float* __restrict__ kv2,
    const float* __restrict__ s2p, float* __restrict__ out)
{
    int idx = blockIdx.x * 256 + threadIdx.x;
    int n   = idx >> 4;
    int s   = idx & 15;
    if (n >= N_NODES) return;

    float4 qa = *(const float4*)(q2p + (size_t)n * 8);
    float4 qb = *(const float4*)(q2p + (size_t)n * 8 + 4);
    int beg = offs[n], end = offs[n + 1];

    float m = -3.402823466e38f, l = 0.f, a[OUTF];
#pragma unroll
    for (int c = 0; c < OUTF; c++) a[c] = 0.f;

    for (int i = beg + s; i < end; i += 16) {
        int src = __float_as_int(erec[i].x);
        const float4* kvp = (const float4*)(kv2 + (size_t)src * 16);
        float4 ka = kvp[0], kb = kvp[1], va = kvp[2], vb = kvp[3];
        float dot = qa.x * ka.x + qa.y * ka.y + qa.z * ka.z + qa.w * ka.w
                  + qb.x * kb.x + qb.y * kb.y + qb.z * kb.z;
        float logit = dot * 0.37796447300922725f;       // 1/sqrt(7)
        float mn = fmaxf(m, logit);
        float sc = __expf(m - mn);
        float pe = __expf(logit - mn);
        l = l * sc + pe;
        a[0] = a[0] * sc + pe * va.x;
        a[1] = a[1] * sc + pe * va.y;
        a[2] = a[2] * sc + pe * va.z;
        a[3] = a[3] * sc + pe * va.w;
        a[4] = a[4] * sc + pe * vb.x;
        a[5] = a[5] * sc + pe * vb.y;
        a[6] = a[6] * sc + pe * vb.z;
        m = mn;
    }

    if (end > beg) {
        float M = dpp_max16(m);                   // lanes past degree hold -inf
        float sc = __expf(m - M);                 // -inf lanes -> 0
        l *= sc;
#pragma unroll
        for (int c = 0; c < OUTF; c++) a[c] *= sc;
        l = dpp_add16(l);
#pragma unroll
        for (int c = 0; c < OUTF; c++) a[c] = dpp_add16(a[c]);
        if (s == 0) {
            float inv = 1.f / fmaxf(l, 1e-16f);
#pragma unroll
            for (int c = 0; c < OUTF; c++)
                out[(size_t)n * OUTF + c] = a[c] * inv + s2p[(size_t)n * 8 + c];
        }
    } else if (s == 0) {
#pragma unroll
        for (int c = 0; c < OUTF; c++)
            out[(size_t)n * OUTF + c] = s2p[(size_t)n * 8 + c];
    }
}

// ----------------------------------------------------------------
extern "C" void kernel_launch(void* const* d_in, const int* in_sizes, int n_in,
                              void* d_out, int out_size, void* d_ws, size_t ws_size,
                              hipStream_t stream)
{
    const float* x    = (const float*)d_in[0];
    const float* ea   = (const float*)d_in[1];
    const int*   ei   = (const int*)d_in[2];
    const float* Wq1  = (const float*)d_in[3];
    const float* bq1  = (const float*)d_in[4];
    const float* Wk1  = (const float*)d_in[5];
    const float* bk1  = (const float*)d_in[6];
    const float* Wv1  = (const float*)d_in[7];
    const float* bv1  = (const float*)d_in[8];
    const float* We1  = (const float*)d_in[9];
    const float* Ws1  = (const float*)d_in[10];
    const float* bs1  = (const float*)d_in[11];
    const float* Wq2  = (const float*)d_in[12];
    const float* bq2  = (const float*)d_in[13];
    const float* Wk2  = (const float*)d_in[14];
    const float* bk2  = (const float*)d_in[15];
    const float* Wv2  = (const float*)d_in[16];
    const float* bv2  = (const float*)d_in[17];
    const float* Ws2  = (const float*)d_in[18];
    const float* bs2  = (const float*)d_in[19];
    float* out = (float*)d_out;

    // workspace layout (f32 words); all segments 16B-aligned.
    float* ws = (float*)d_ws;
    float*          q1  = ws;                                   // N*64 f32
    float*          s1  = q1 + (size_t)N_NODES * HC;            // N*64 f32
    unsigned short* kv1 = (unsigned short*)(s1 + (size_t)N_NODES * HC); // N*128 bf16
    float*          hbuf = q1;   // alias: attn1 reads q1 row n then writes h row n
    float4* erec = (float4*)((float*)kv1 + (size_t)N_NODES * HC);  // E x 16B
    float*  q2p  = (float*)(erec + N_EDGES);         // N*8
    float*  kv2  = q2p + (size_t)N_NODES * 8;        // N*16
    float*  s2p  = kv2 + (size_t)N_NODES * 16;       // N*8
    unsigned short* Wt = (unsigned short*)(s2p + (size_t)N_NODES * 8);  // 32768 bf16
    int*    count  = (int*)(Wt + 4 * HC * IN_F);     // N
    int*    offs   = count + N_NODES;                // N+1
    int*    cursor = offs + N_NODES + 1;             // N
    int*    pre    = cursor + N_NODES;               // N
    int*    bsum   = pre + N_NODES;                  // NSB
    int*    bofs   = bsum + NSB;                     // NSB

    const int eb = (N_EDGES + 255) / 256;
    const int nwave_blocks = (N_NODES * 64 + 255) / 256;

    init_kernel<<<(N_NODES + 255) / 256, 256, 0, stream>>>(count);
    convert_w_kernel<<<(4 * HC * IN_F + 255) / 256, 256, 0, stream>>>(
        Wq1, Wk1, Wv1, Ws1, Wt);
    hist_kernel<<<eb, 256, 0, stream>>>(ei, count);

    proj1_mfma_kernel<<<N_NODES / 16, 256, 0, stream>>>(
        x, Wt, bq1, bk1, bv1, bs1, q1, kv1, s1);

    scan1_kernel<<<NSB, 256, 0, stream>>>(count, pre, bsum);
    scan2_kernel<<<1, 256, 0, stream>>>(bsum, bofs);
    scan3_kernel<<<NSB, 256, 0, stream>>>(pre, bofs, offs, cursor);
    scatter_kernel<<<eb, 256, 0, stream>>>(ei, ea, cursor, erec);

    attn1_kernel<<<nwave_blocks, 256, 0, stream>>>(
        offs, erec, We1, q1, kv1, s1, hbuf);

    proj2_kernel<<<(N_NODES + 255) / 256, 256, 0, stream>>>(
        hbuf, Wq2, bq2, Wk2, bk2, Wv2, bv2, Ws2, bs2, q2p, kv2, s2p);

    attn2_kernel<<<(N_NODES * 16 + 255) / 256, 256, 0, stream>>>(
        offs, erec, q2p, kv2, s2p, out);
}

// Round 15
// 214.154 us; speedup vs baseline: 1.3207x; 1.0019x over previous
//
#include <hip/hip_runtime.h>

// TransformerClassification: 2-layer PyG TransformerConv GNN on MI355X.
// Round 15: (1) edge record 16B -> 8B {src, bf16 ea0, bf16 ea1} — scatter's
// 51MB WRITE_SIZE was 800K x 64B partial-line transactions; smaller records
// halve sectors and halve attn1's erec stream. (2) proj1_mfma (compute-bound)
// fused into scatter's (memory-bound) launch window as a heterogeneous grid.

#define N_NODES 50000
#define N_EDGES 800000
#define IN_F    128
#define HC      64      // heads*ch layer1
#define NH      4
#define CH      16
#define OUTF    7

#define NSB ((N_NODES + 255) / 256)   // 196 scan blocks
#define P1_BLOCKS (N_NODES / 16)      // 3125 proj1 blocks
#define SC_BLOCKS ((N_EDGES + 255) / 256)  // 3125 scatter blocks

typedef __attribute__((ext_vector_type(8))) short bf16x8;
typedef __attribute__((ext_vector_type(4))) float f32x4;

__device__ __forceinline__ unsigned short f2bf(float f) {
    unsigned u = __float_as_uint(f);
    unsigned r = u + 0x7FFFu + ((u >> 16) & 1u);   // round-to-nearest-even
    return (unsigned short)(r >> 16);
}
__device__ __forceinline__ float bflo(unsigned u) { return __uint_as_float(u << 16); }
__device__ __forceinline__ float bfhi(unsigned u) { return __uint_as_float(u & 0xFFFF0000u); }

// ---------------- DPP helpers ----------------
__device__ __forceinline__ float dpp_add16(float x) {
    int t;
    t = __builtin_amdgcn_update_dpp(0, __float_as_int(x), 0xB1, 0xF, 0xF, false);
    x += __int_as_float(t);
    t = __builtin_amdgcn_update_dpp(0, __float_as_int(x), 0x4E, 0xF, 0xF, false);
    x += __int_as_float(t);
    t = __builtin_amdgcn_update_dpp(0, __float_as_int(x), 0x124, 0xF, 0xF, false);
    x += __int_as_float(t);
    t = __builtin_amdgcn_update_dpp(0, __float_as_int(x), 0x128, 0xF, 0xF, false);
    x += __int_as_float(t);
    return x;
}
__device__ __forceinline__ float dpp_max16(float x) {
    int t;
    t = __builtin_amdgcn_update_dpp(0, __float_as_int(x), 0xB1, 0xF, 0xF, false);
    x = fmaxf(x, __int_as_float(t));
    t = __builtin_amdgcn_update_dpp(0, __float_as_int(x), 0x4E, 0xF, 0xF, false);
    x = fmaxf(x, __int_as_float(t));
    t = __builtin_amdgcn_update_dpp(0, __float_as_int(x), 0x124, 0xF, 0xF, false);
    x = fmaxf(x, __int_as_float(t));
    t = __builtin_amdgcn_update_dpp(0, __float_as_int(x), 0x128, 0xF, 0xF, false);
    x = fmaxf(x, __int_as_float(t));
    return x;
}
__device__ __forceinline__ float dpp_add4(float x) {
    int t;
    t = __builtin_amdgcn_update_dpp(0, __float_as_int(x), 0xB1, 0xF, 0xF, false);
    x += __int_as_float(t);
    t = __builtin_amdgcn_update_dpp(0, __float_as_int(x), 0x4E, 0xF, 0xF, false);
    x += __int_as_float(t);
    return x;
}

// ---------------------------------------------------------------- init: zero the histogram
__global__ __launch_bounds__(256) void init_kernel(int* __restrict__ count)
{
    int i = blockIdx.x * 256 + threadIdx.x;
    if (i < N_NODES) count[i] = 0;
}

// ---------------------------------------------------------------- convert W -> Wt[mtx][col][k] bf16
__global__ __launch_bounds__(256) void convert_w_kernel(
    const float* __restrict__ Wq, const float* __restrict__ Wk,
    const float* __restrict__ Wv, const float* __restrict__ Ws,
    unsigned short* __restrict__ Wt)
{
    int i = blockIdx.x * 256 + threadIdx.x;   // 4*64*128 = 32768
    if (i >= 4 * HC * IN_F) return;
    int m   = i >> 13;          // /8192
    int col = (i >> 7) & 63;
    int k   = i & 127;
    const float* W = (m == 0) ? Wq : (m == 1) ? Wk : (m == 2) ? Wv : Ws;
    Wt[i] = f2bf(W[k * HC + col]);
}

// ---------------------------------------------------------------- histogram of dst
__global__ __launch_bounds__(256) void hist_kernel(
    const int* __restrict__ ei, int* __restrict__ count)
{
    int e = blockIdx.x * 256 + threadIdx.x;
    if (e < N_EDGES) atomicAdd(count + ei[N_EDGES + e], 1);
}

// ---------------------------------------------------------------- scan phase 1
__global__ __launch_bounds__(256) void scan1_kernel(
    const int* __restrict__ count, int* __restrict__ pre, int* __restrict__ bsum)
{
    __shared__ int sdata[256];
    const int t = threadIdx.x;
    const int i = blockIdx.x * 256 + t;
    int v = (i < N_NODES) ? count[i] : 0;
    sdata[t] = v;
    __syncthreads();
    for (int d = 1; d < 256; d <<= 1) {
        int u = (t >= d) ? sdata[t - d] : 0;
        __syncthreads();
        sdata[t] += u;
        __syncthreads();
    }
    if (i < N_NODES) pre[i] = sdata[t] - v;
    if (t == 255) bsum[blockIdx.x] = sdata[255];
}

// ---------------------------------------------------------------- scan phase 2 (1 block)
__global__ __launch_bounds__(256) void scan2_kernel(
    int* __restrict__ bsum, int* __restrict__ bofs)
{
    __shared__ int sdata[256];
    const int t = threadIdx.x;
    int v = (t < NSB) ? bsum[t] : 0;
    sdata[t] = v;
    __syncthreads();
    for (int d = 1; d < 256; d <<= 1) {
        int u = (t >= d) ? sdata[t - d] : 0;
        __syncthreads();
        sdata[t] += u;
        __syncthreads();
    }
    if (t < NSB) bofs[t] = sdata[t] - v;
}

// ---------------------------------------------------------------- scan phase 3
__global__ __launch_bounds__(256) void scan3_kernel(
    const int* __restrict__ pre, const int* __restrict__ bofs,
    int* __restrict__ offs, int* __restrict__ cursor)
{
    const int i = blockIdx.x * 256 + threadIdx.x;
    if (i < N_NODES) {
        int o = pre[i] + bofs[i >> 8];
        offs[i] = o; cursor[i] = o;
    }
    if (i == 0) offs[N_NODES] = N_EDGES;
}

// ---------------------------------------------------------------- fused: proj1 MFMA | edge scatter
// blocks [0, P1_BLOCKS): 16 nodes x 256 cols MFMA projection (4 waves = 4 mtx).
// blocks [P1_BLOCKS, +SC_BLOCKS): scatter 256 edges to 8B dst-sorted records.
__global__ __launch_bounds__(256) void proj1_scatter_kernel(
    const float* __restrict__ x, const unsigned short* __restrict__ Wt,
    const float* __restrict__ bq, const float* __restrict__ bk,
    const float* __restrict__ bv, const float* __restrict__ bs,
    float* __restrict__ q1, unsigned short* __restrict__ kv1,
    float* __restrict__ s1,
    const int* __restrict__ ei, const float* __restrict__ ea,
    int* __restrict__ cursor, uint2* __restrict__ erec)
{
    __shared__ unsigned short xs[16][136];
    const int t = threadIdx.x;

    if (blockIdx.x >= P1_BLOCKS) {
        int e = (blockIdx.x - P1_BLOCKS) * 256 + t;
        if (e < N_EDGES) {
            int dst = ei[N_EDGES + e];
            int pos = atomicAdd(cursor + dst, 1);
            uint2 r;
            r.x = (unsigned)ei[e];
            r.y = (unsigned)f2bf(ea[(size_t)e * 2])
                | ((unsigned)f2bf(ea[(size_t)e * 2 + 1]) << 16);
            erec[pos] = r;
        }
        return;
    }

    const int w = t >> 6, lane = t & 63;
    const int n0 = blockIdx.x * 16;
    const int col16 = lane & 15, kg = lane >> 4;

    // B-fragments: 4 k-chunks x 4 n-tiles, from global (shared across blocks)
    bf16x8 bfrag[4][4];
#pragma unroll
    for (int tt = 0; tt < 4; tt++) {
        const unsigned short* bp = Wt + ((size_t)(w * 64 + tt * 16 + col16) * IN_F) + 8 * kg;
#pragma unroll
        for (int kc = 0; kc < 4; kc++)
            bfrag[kc][tt] = *(const bf16x8*)(bp + kc * 32);
    }

    // stage this block's 16 x-rows as bf16 into LDS
    {
        int row = t >> 4, k8 = (t & 15) * 8;
        const float* xp = x + (size_t)(n0 + row) * IN_F + k8;
        float4 f0 = *(const float4*)xp;
        float4 f1 = *(const float4*)(xp + 4);
        uint4 pk;
        pk.x = f2bf(f0.x) | ((unsigned)f2bf(f0.y) << 16);
        pk.y = f2bf(f0.z) | ((unsigned)f2bf(f0.w) << 16);
        pk.z = f2bf(f1.x) | ((unsigned)f2bf(f1.y) << 16);
        pk.w = f2bf(f1.z) | ((unsigned)f2bf(f1.w) << 16);
        *(uint4*)&xs[row][k8] = pk;
    }
    __syncthreads();

    f32x4 acc[4] = { {0,0,0,0}, {0,0,0,0}, {0,0,0,0}, {0,0,0,0} };
#pragma unroll
    for (int kc = 0; kc < 4; kc++) {
        bf16x8 a = *(const bf16x8*)&xs[col16][kc * 32 + 8 * kg];
#pragma unroll
        for (int tt = 0; tt < 4; tt++)
            acc[tt] = __builtin_amdgcn_mfma_f32_16x16x32_bf16(a, bfrag[kc][tt], acc[tt], 0, 0, 0);
    }

    if (w == 0 || w == 3) {
        const float* Bm = (w == 0) ? bq : bs;
        float*       Om = (w == 0) ? q1 : s1;
#pragma unroll
        for (int tt = 0; tt < 4; tt++) {
            int col = tt * 16 + col16;
            float bias = Bm[col];
#pragma unroll
            for (int r = 0; r < 4; r++) {
                int node = n0 + kg * 4 + r;
                Om[(size_t)node * HC + col] = acc[tt][r] + bias;
            }
        }
    } else {
        const float* Bm = (w == 1) ? bk : bv;
        const int cbase = (w == 1) ? 0 : 64;
#pragma unroll
        for (int tt = 0; tt < 4; tt++) {
            int col = tt * 16 + col16;
            float bias = Bm[col];
#pragma unroll
            for (int r = 0; r < 4; r++) {
                int node = n0 + kg * 4 + r;
                kv1[(size_t)node * 128 + cbase + col] = f2bf(acc[tt][r] + bias);
            }
        }
    }
}

// ---------------------------------------------------------------- layer1 attention: one wave per dst node
// 4 edges/wave (g), 16 lanes/edge (s owns channels 4s..4s+3).
// erec is 8B {src, bf16 ea0|ea1}; kv1 gather is bf16.
__global__ __launch_bounds__(256) void attn1_kernel(
    const int* __restrict__ offs, const uint2* __restrict__ erec,
    const float* __restrict__ We,
    const float* __restrict__ q1, const unsigned short* __restrict__ kv1,
    const float* __restrict__ s1, float* __restrict__ h)
{
    int n    = (blockIdx.x * 256 + threadIdx.x) >> 6;
    int lane = threadIdx.x & 63;
    if (n >= N_NODES) return;
    const int g = lane >> 4;     // edge slot 0..3
    const int s = lane & 15;     // channel quad: channels 4s..4s+3

    const float4 qv  = *(const float4*)(q1 + (size_t)n * HC + s * 4);
    const float4 We0 = *(const float4*)(We + s * 4);
    const float4 We1 = *(const float4*)(We + HC + s * 4);
    const int beg = offs[n], end = offs[n + 1];

    float m = -3.402823466e38f, l = 0.f;
    float4 acc = make_float4(0.f, 0.f, 0.f, 0.f);

    for (int base = beg; base < end; base += 4) {
        int i = base + g;
        bool valid = (i < end);
        uint2 r = erec[valid ? i : beg];
        int src = (int)r.x;
        float ea0 = bflo(r.y), ea1 = bfhi(r.y);
        const unsigned short* kvp = kv1 + ((size_t)src << 7) + (s << 2);
        uint2 kraw = *(const uint2*)kvp;
        uint2 vraw = *(const uint2*)(kvp + 64);
        float k0 = bflo(kraw.x), k1 = bfhi(kraw.x);
        float k2 = bflo(kraw.y), k3 = bfhi(kraw.y);
        float v0 = bflo(vraw.x), v1 = bfhi(vraw.x);
        float v2 = bflo(vraw.y), v3 = bfhi(vraw.y);
        float4 ec = make_float4(ea0 * We0.x + ea1 * We1.x,
                                ea0 * We0.y + ea1 * We1.y,
                                ea0 * We0.z + ea1 * We1.z,
                                ea0 * We0.w + ea1 * We1.w);
        float d = qv.x * (k0 + ec.x) + qv.y * (k1 + ec.y)
                + qv.z * (k2 + ec.z) + qv.w * (k3 + ec.w);
        d = dpp_add4(d);                          // head dot (16 channels)
        float logit = valid ? d * 0.25f : -3.402823466e38f;   // 1/sqrt(16)
        float mn = fmaxf(m, logit);
        float sm = __expf(m - mn);
        float pe = valid ? __expf(logit - mn) : 0.f;
        l = l * sm + pe;
        acc.x = acc.x * sm + pe * (v0 + ec.x);
        acc.y = acc.y * sm + pe * (v1 + ec.y);
        acc.z = acc.z * sm + pe * (v2 + ec.z);
        acc.w = acc.w * sm + pe * (v3 + ec.w);
        m = mn;
    }

    if (end > beg) {
        float M = fmaxf(m, __shfl_xor(m, 16));
        M = fmaxf(M, __shfl_xor(M, 32));
        float sc = __expf(m - M);                 // empty group: -inf -> 0
        l *= sc; acc.x *= sc; acc.y *= sc; acc.z *= sc; acc.w *= sc;
        l += __shfl_xor(l, 16);  l += __shfl_xor(l, 32);
        acc.x += __shfl_xor(acc.x, 16); acc.x += __shfl_xor(acc.x, 32);
        acc.y += __shfl_xor(acc.y, 16); acc.y += __shfl_xor(acc.y, 32);
        acc.z += __shfl_xor(acc.z, 16); acc.z += __shfl_xor(acc.z, 32);
        acc.w += __shfl_xor(acc.w, 16); acc.w += __shfl_xor(acc.w, 32);
        if (lane < 16) {
            float inv = 1.f / l;
            float4 sk = *(const float4*)(s1 + (size_t)n * HC + s * 4);
            float4 o;
            o.x = acc.x * inv + sk.x;
            o.y = acc.y * inv + sk.y;
            o.z = acc.z * inv + sk.z;
            o.w = acc.w * inv + sk.w;
            o.x = o.x > 0.f ? o.x : expm1f(o.x);
            o.y = o.y > 0.f ? o.y : expm1f(o.y);
            o.z = o.z > 0.f ? o.z : expm1f(o.z);
            o.w = o.w > 0.f ? o.w : expm1f(o.w);
            *(float4*)(h + (size_t)n * HC + s * 4) = o;
        }
    } else if (lane < 16) {
        float4 sk = *(const float4*)(s1 + (size_t)n * HC + s * 4);
        float4 o;
        o.x = sk.x > 0.f ? sk.x : expm1f(sk.x);
        o.y = sk.y > 0.f ? sk.y : expm1f(sk.y);
        o.z = sk.z > 0.f ? sk.z : expm1f(sk.z);
        o.w = sk.w > 0.f ? sk.w : expm1f(sk.w);
        *(float4*)(h + (size_t)n * HC + s * 4) = o;
    }
}

// ---------------------------------------------------------------- layer2 node projections (64 -> 28), thread-per-node
__global__ __launch_bounds__(256) void proj2_kernel(
    const float* __restrict__ h,
    const float* __restrict__ Wq, const float* __restrict__ bq,
    const float* __restrict__ Wk, const float* __restrict__ bk,
    const float* __restrict__ Wv, const float* __restrict__ bv,
    const float* __restrict__ Ws, const float* __restrict__ bs,
    float* __restrict__ q2p, float* __restrict__ kv2, float* __restrict__ s2p)
{
    __shared__ float Wsm[HC][4][8];   // 8 KB
    __shared__ float Bsm[4][8];
    const int t = threadIdx.x;

    for (int j = t; j < HC * 28; j += 256) {
        int i = j / 28, r = j % 28, mtx = r / 7, c = r % 7;
        const float* W = (mtx == 0) ? Wq : (mtx == 1) ? Wk : (mtx == 2) ? Wv : Ws;
        Wsm[i][mtx][c] = W[i * OUTF + c];
    }
    for (int j = t; j < HC * 4; j += 256)          // zero the c=7 pad
        Wsm[j >> 2][j & 3][7] = 0.f;
    if (t < 32) {
        int mtx = t >> 3, c = t & 7;
        const float* B = (mtx == 0) ? bq : (mtx == 1) ? bk : (mtx == 2) ? bv : bs;
        Bsm[mtx][c] = (c < 7) ? B[c] : 0.f;
    }
    __syncthreads();

    int n = blockIdx.x * 256 + t;
    if (n >= N_NODES) return;

    float acc[4][8];
#pragma unroll
    for (int mtx = 0; mtx < 4; mtx++)
#pragma unroll
        for (int c = 0; c < 8; c++) acc[mtx][c] = Bsm[mtx][c];

    const float4* hp = (const float4*)(h + (size_t)n * HC);
#pragma unroll 4
    for (int i4 = 0; i4 < 16; i4++) {
        float4 hv = hp[i4];
        float hx[4] = { hv.x, hv.y, hv.z, hv.w };
#pragma unroll
        for (int e = 0; e < 4; e++) {
            int i = i4 * 4 + e;
#pragma unroll
            for (int mtx = 0; mtx < 4; mtx++) {
                float4 wa = *(const float4*)&Wsm[i][mtx][0];
                float4 wb = *(const float4*)&Wsm[i][mtx][4];
                acc[mtx][0] += hx[e] * wa.x; acc[mtx][1] += hx[e] * wa.y;
                acc[mtx][2] += hx[e] * wa.z; acc[mtx][3] += hx[e] * wa.w;
                acc[mtx][4] += hx[e] * wb.x; acc[mtx][5] += hx[e] * wb.y;
                acc[mtx][6] += hx[e] * wb.z; acc[mtx][7] += hx[e] * wb.w;
            }
        }
    }

    float4* q2v = (float4*)(q2p + (size_t)n * 8);
    q2v[0] = make_float4(acc[0][0], acc[0][1], acc[0][2], acc[0][3]);
    q2v[1] = make_float4(acc[0][4], acc[0][5], acc[0][6], acc[0][7]);
    float4* kvv = (float4*)(kv2 + (size_t)n * 16);
    kvv[0] = make_float4(acc[1][0], acc[1][1], acc[1][2], acc[1][3]);
    kvv[1] = make_float4(acc[1][4], acc[1][5], acc[1][6], acc[1][7]);
    kvv[2] = make_float4(acc[2][0], acc[2][1], acc[2][2], acc[2][3]);
    kvv[3] = make_float4(acc[2][4], acc[2][5], acc[2][6], acc[2][7]);
    float4* s2v = (float4*)(s2p + (size_t)n * 8);
    s2v[0] = make_float4(acc[3][0], acc[3][1], acc[3][2], acc[3][3]);
    s2v[1] = make_float4(acc[3][4], acc[3][5], acc[3][6], acc[3][7]);
}

// ---------------------------------------------------------------- layer2 attention: 4 nodes/wave, 16 lanes/node
__global__ __launch_bounds__(256) void attn2_kernel(
    const int* __restrict__ offs, const uint2* __restrict__ erec,
    const float* __restrict__ q2p, const float* __restrict__ kv2,
    const float* __restrict__ s2p, float* __restrict__ out)
{
    int idx = blockIdx.x * 256 + threadIdx.x;
    int n   = idx >> 4;
    int s   = idx & 15;
    if (n >= N_NODES) return;

    float4 qa = *(const float4*)(q2p + (size_t)n * 8);
    float4 qb = *(const float4*)(q2p + (size_t)n * 8 + 4);
    int beg = offs[n], end = offs[n + 1];

    float m = -3.402823466e38f, l = 0.f, a[OUTF];
#pragma unroll
    for (int c = 0; c < OUTF; c++) a[c] = 0.f;

    for (int i = beg + s; i < end; i += 16) {
        int src = (int)erec[i].x;
        const float4* kvp = (const float4*)(kv2 + (size_t)src * 16);
        float4 ka = kvp[0], kb = kvp[1], va = kvp[2], vb = kvp[3];
        float dot = qa.x * ka.x + qa.y * ka.y + qa.z * ka.z + qa.w * ka.w
                  + qb.x * kb.x + qb.y * kb.y + qb.z * kb.z;
        float logit = dot * 0.37796447300922725f;       // 1/sqrt(7)
        float mn = fmaxf(m, logit);
        float sc = __expf(m - mn);
        float pe = __expf(logit - mn);
        l = l * sc + pe;
        a[0] = a[0] * sc + pe * va.x;
        a[1] = a[1] * sc + pe * va.y;
        a[2] = a[2] * sc + pe * va.z;
        a[3] = a[3] * sc + pe * va.w;
        a[4] = a[4] * sc + pe * vb.x;
        a[5] = a[5] * sc + pe * vb.y;
        a[6] = a[6] * sc + pe * vb.z;
        m = mn;
    }

    if (end > beg) {
        float M = dpp_max16(m);                   // lanes past degree hold -inf
        float sc = __expf(m - M);                 // -inf lanes -> 0
        l *= sc;
#pragma unroll
        for (int c = 0; c < OUTF; c++) a[c] *= sc;
        l = dpp_add16(l);
#pragma unroll
        for (int c = 0; c < OUTF; c++) a[c] = dpp_add16(a[c]);
        if (s == 0) {
            float inv = 1.f / fmaxf(l, 1e-16f);
#pragma unroll
            for (int c = 0; c < OUTF; c++)
                out[(size_t)n * OUTF + c] = a[c] * inv + s2p[(size_t)n * 8 + c];
        }
    } else if (s == 0) {
#pragma unroll
        for (int c = 0; c < OUTF; c++)
            out[(size_t)n * OUTF + c] = s2p[(size_t)n * 8 + c];
    }
}

// ----------------------------------------------------------------
extern "C" void kernel_launch(void* const* d_in, const int* in_sizes, int n_in,
                              void* d_out, int out_size, void* d_ws, size_t ws_size,
                              hipStream_t stream)
{
    const float* x    = (const float*)d_in[0];
    const float* ea   = (const float*)d_in[1];
    const int*   ei   = (const int*)d_in[2];
    const float* Wq1  = (const float*)d_in[3];
    const float* bq1  = (const float*)d_in[4];
    const float* Wk1  = (const float*)d_in[5];
    const float* bk1  = (const float*)d_in[6];
    const float* Wv1  = (const float*)d_in[7];
    const float* bv1  = (const float*)d_in[8];
    const float* We1  = (const float*)d_in[9];
    const float* Ws1  = (const float*)d_in[10];
    const float* bs1  = (const float*)d_in[11];
    const float* Wq2  = (const float*)d_in[12];
    const float* bq2  = (const float*)d_in[13];
    const float* Wk2  = (const float*)d_in[14];
    const float* bk2  = (const float*)d_in[15];
    const float* Wv2  = (const float*)d_in[16];
    const float* bv2  = (const float*)d_in[17];
    const float* Ws2  = (const float*)d_in[18];
    const float* bs2  = (const float*)d_in[19];
    float* out = (float*)d_out;

    // workspace layout (f32 words); all segments 16B-aligned.
    float* ws = (float*)d_ws;
    float*          q1  = ws;                                   // N*64 f32
    float*          s1  = q1 + (size_t)N_NODES * HC;            // N*64 f32
    unsigned short* kv1 = (unsigned short*)(s1 + (size_t)N_NODES * HC); // N*128 bf16
    float*          hbuf = q1;   // alias: attn1 reads q1 row n then writes h row n
    uint2* erec = (uint2*)((float*)kv1 + (size_t)N_NODES * HC); // E x 8B
    float*  q2p  = (float*)(erec + N_EDGES);         // N*8
    float*  kv2  = q2p + (size_t)N_NODES * 8;        // N*16
    float*  s2p  = kv2 + (size_t)N_NODES * 16;       // N*8
    unsigned short* Wt = (unsigned short*)(s2p + (size_t)N_NODES * 8);  // 32768 bf16
    int*    count  = (int*)(Wt + 4 * HC * IN_F);     // N
    int*    offs   = count + N_NODES;                // N+1
    int*    cursor = offs + N_NODES + 1;             // N
    int*    pre    = cursor + N_NODES;               // N
    int*    bsum   = pre + N_NODES;                  // NSB
    int*    bofs   = bsum + NSB;                     // NSB

    const int eb = (N_EDGES + 255) / 256;
    const int nwave_blocks = (N_NODES * 64 + 255) / 256;

    init_kernel<<<(N_NODES + 255) / 256, 256, 0, stream>>>(count);
    convert_w_kernel<<<(4 * HC * IN_F + 255) / 256, 256, 0, stream>>>(
        Wq1, Wk1, Wv1, Ws1, Wt);
    hist_kernel<<<eb, 256, 0, stream>>>(ei, count);

    scan1_kernel<<<NSB, 256, 0, stream>>>(count, pre, bsum);
    scan2_kernel<<<1, 256, 0, stream>>>(bsum, bofs);
    scan3_kernel<<<NSB, 256, 0, stream>>>(pre, bofs, offs, cursor);

    proj1_scatter_kernel<<<P1_BLOCKS + SC_BLOCKS, 256, 0, stream>>>(
        x, Wt, bq1, bk1, bv1, bs1, q1, kv1, s1, ei, ea, cursor, erec);

    attn1_kernel<<<nwave_blocks, 256, 0, stream>>>(
        offs, erec, We1, q1, kv1, s1, hbuf);

    proj2_kernel<<<(N_NODES + 255) / 256, 256, 0, stream>>>(
        hbuf, Wq2, bq2, Wk2, bk2, Wv2, bv2, Ws2, bs2, q2p, kv2, s2p);

    attn2_kernel<<<(N_NODES * 16 + 255) / 256, 256, 0, stream>>>(
        offs, erec, q2p, kv2, s2p, out);
}

// Round 16
// 183.861 us; speedup vs baseline: 1.5383x; 1.1648x over previous
//
#include <hip/hip_runtime.h>

// TransformerClassification: 2-layer PyG TransformerConv GNN on MI355X.
// Round 16: two-phase binned scatter. Old scatter = 800K random 8B writes
// -> 51MB of 64B transactions (measured r14/r15; record size irrelevant).
// scatterA: per-block LDS histogram over 500 coarse buckets (dst/100) +
// bulk range reservation -> block-local contiguous writes (~13MB).
// sortB: one block per bucket, LDS per-dst cursors, L2-local final placement.
// proj1_mfma un-fused (r15 fusion was neutral + starved MFMA).

#define N_NODES 50000
#define N_EDGES 800000
#define IN_F    128
#define HC      64      // heads*ch layer1
#define NH      4
#define CH      16
#define OUTF    7

#define NSB ((N_NODES + 255) / 256)   // 196 scan blocks
#define DPB 100                        // dsts per bucket
#define NBK (N_NODES / DPB)            // 500 buckets
#define SC_EPB 4096
#define SCA_BLOCKS ((N_EDGES + SC_EPB - 1) / SC_EPB)   // 196

typedef __attribute__((ext_vector_type(8))) short bf16x8;
typedef __attribute__((ext_vector_type(4))) float f32x4;

__device__ __forceinline__ unsigned short f2bf(float f) {
    unsigned u = __float_as_uint(f);
    unsigned r = u + 0x7FFFu + ((u >> 16) & 1u);   // round-to-nearest-even
    return (unsigned short)(r >> 16);
}
__device__ __forceinline__ float bflo(unsigned u) { return __uint_as_float(u << 16); }
__device__ __forceinline__ float bfhi(unsigned u) { return __uint_as_float(u & 0xFFFF0000u); }

// ---------------- DPP helpers ----------------
__device__ __forceinline__ float dpp_add16(float x) {
    int t;
    t = __builtin_amdgcn_update_dpp(0, __float_as_int(x), 0xB1, 0xF, 0xF, false);
    x += __int_as_float(t);
    t = __builtin_amdgcn_update_dpp(0, __float_as_int(x), 0x4E, 0xF, 0xF, false);
    x += __int_as_float(t);
    t = __builtin_amdgcn_update_dpp(0, __float_as_int(x), 0x124, 0xF, 0xF, false);
    x += __int_as_float(t);
    t = __builtin_amdgcn_update_dpp(0, __float_as_int(x), 0x128, 0xF, 0xF, false);
    x += __int_as_float(t);
    return x;
}
__device__ __forceinline__ float dpp_max16(float x) {
    int t;
    t = __builtin_amdgcn_update_dpp(0, __float_as_int(x), 0xB1, 0xF, 0xF, false);
    x = fmaxf(x, __int_as_float(t));
    t = __builtin_amdgcn_update_dpp(0, __float_as_int(x), 0x4E, 0xF, 0xF, false);
    x = fmaxf(x, __int_as_float(t));
    t = __builtin_amdgcn_update_dpp(0, __float_as_int(x), 0x124, 0xF, 0xF, false);
    x = fmaxf(x, __int_as_float(t));
    t = __builtin_amdgcn_update_dpp(0, __float_as_int(x), 0x128, 0xF, 0xF, false);
    x = fmaxf(x, __int_as_float(t));
    return x;
}
__device__ __forceinline__ float dpp_add4(float x) {
    int t;
    t = __builtin_amdgcn_update_dpp(0, __float_as_int(x), 0xB1, 0xF, 0xF, false);
    x += __int_as_float(t);
    t = __builtin_amdgcn_update_dpp(0, __float_as_int(x), 0x4E, 0xF, 0xF, false);
    x += __int_as_float(t);
    return x;
}

// ---------------------------------------------------------------- init: zero the histogram
__global__ __launch_bounds__(256) void init_kernel(int* __restrict__ count)
{
    int i = blockIdx.x * 256 + threadIdx.x;
    if (i < N_NODES) count[i] = 0;
}

// ---------------------------------------------------------------- convert W -> Wt[mtx][col][k] bf16
__global__ __launch_bounds__(256) void convert_w_kernel(
    const float* __restrict__ Wq, const float* __restrict__ Wk,
    const float* __restrict__ Wv, const float* __restrict__ Ws,
    unsigned short* __restrict__ Wt)
{
    int i = blockIdx.x * 256 + threadIdx.x;   // 4*64*128 = 32768
    if (i >= 4 * HC * IN_F) return;
    int m   = i >> 13;          // /8192
    int col = (i >> 7) & 63;
    int k   = i & 127;
    const float* W = (m == 0) ? Wq : (m == 1) ? Wk : (m == 2) ? Wv : Ws;
    Wt[i] = f2bf(W[k * HC + col]);
}

// ---------------------------------------------------------------- histogram of dst
__global__ __launch_bounds__(256) void hist_kernel(
    const int* __restrict__ ei, int* __restrict__ count)
{
    int e = blockIdx.x * 256 + threadIdx.x;
    if (e < N_EDGES) atomicAdd(count + ei[N_EDGES + e], 1);
}

// ---------------------------------------------------------------- layer1 projections via MFMA
// 16 nodes x 256 cols per block; wave w = matrix w. q,s -> f32; k,v -> kv1 bf16.
__global__ __launch_bounds__(256) void proj1_mfma_kernel(
    const float* __restrict__ x, const unsigned short* __restrict__ Wt,
    const float* __restrict__ bq, const float* __restrict__ bk,
    const float* __restrict__ bv, const float* __restrict__ bs,
    float* __restrict__ q1, unsigned short* __restrict__ kv1,
    float* __restrict__ s1)
{
    __shared__ unsigned short xs[16][136];
    const int t = threadIdx.x;
    const int w = t >> 6, lane = t & 63;
    const int n0 = blockIdx.x * 16;
    const int col16 = lane & 15, kg = lane >> 4;

    bf16x8 bfrag[4][4];
#pragma unroll
    for (int tt = 0; tt < 4; tt++) {
        const unsigned short* bp = Wt + ((size_t)(w * 64 + tt * 16 + col16) * IN_F) + 8 * kg;
#pragma unroll
        for (int kc = 0; kc < 4; kc++)
            bfrag[kc][tt] = *(const bf16x8*)(bp + kc * 32);
    }

    {
        int row = t >> 4, k8 = (t & 15) * 8;
        const float* xp = x + (size_t)(n0 + row) * IN_F + k8;
        float4 f0 = *(const float4*)xp;
        float4 f1 = *(const float4*)(xp + 4);
        uint4 pk;
        pk.x = f2bf(f0.x) | ((unsigned)f2bf(f0.y) << 16);
        pk.y = f2bf(f0.z) | ((unsigned)f2bf(f0.w) << 16);
        pk.z = f2bf(f1.x) | ((unsigned)f2bf(f1.y) << 16);
        pk.w = f2bf(f1.z) | ((unsigned)f2bf(f1.w) << 16);
        *(uint4*)&xs[row][k8] = pk;
    }
    __syncthreads();

    f32x4 acc[4] = { {0,0,0,0}, {0,0,0,0}, {0,0,0,0}, {0,0,0,0} };
#pragma unroll
    for (int kc = 0; kc < 4; kc++) {
        bf16x8 a = *(const bf16x8*)&xs[col16][kc * 32 + 8 * kg];
#pragma unroll
        for (int tt = 0; tt < 4; tt++)
            acc[tt] = __builtin_amdgcn_mfma_f32_16x16x32_bf16(a, bfrag[kc][tt], acc[tt], 0, 0, 0);
    }

    if (w == 0 || w == 3) {
        const float* Bm = (w == 0) ? bq : bs;
        float*       Om = (w == 0) ? q1 : s1;
#pragma unroll
        for (int tt = 0; tt < 4; tt++) {
            int col = tt * 16 + col16;
            float bias = Bm[col];
#pragma unroll
            for (int r = 0; r < 4; r++) {
                int node = n0 + kg * 4 + r;
                Om[(size_t)node * HC + col] = acc[tt][r] + bias;
            }
        }
    } else {
        const float* Bm = (w == 1) ? bk : bv;
        const int cbase = (w == 1) ? 0 : 64;
#pragma unroll
        for (int tt = 0; tt < 4; tt++) {
            int col = tt * 16 + col16;
            float bias = Bm[col];
#pragma unroll
            for (int r = 0; r < 4; r++) {
                int node = n0 + kg * 4 + r;
                kv1[(size_t)node * 128 + cbase + col] = f2bf(acc[tt][r] + bias);
            }
        }
    }
}

// ---------------------------------------------------------------- scan phase 1
__global__ __launch_bounds__(256) void scan1_kernel(
    const int* __restrict__ count, int* __restrict__ pre, int* __restrict__ bsum)
{
    __shared__ int sdata[256];
    const int t = threadIdx.x;
    const int i = blockIdx.x * 256 + t;
    int v = (i < N_NODES) ? count[i] : 0;
    sdata[t] = v;
    __syncthreads();
    for (int d = 1; d < 256; d <<= 1) {
        int u = (t >= d) ? sdata[t - d] : 0;
        __syncthreads();
        sdata[t] += u;
        __syncthreads();
    }
    if (i < N_NODES) pre[i] = sdata[t] - v;
    if (t == 255) bsum[blockIdx.x] = sdata[255];
}

// ---------------------------------------------------------------- scan phase 2 (1 block)
__global__ __launch_bounds__(256) void scan2_kernel(
    int* __restrict__ bsum, int* __restrict__ bofs)
{
    __shared__ int sdata[256];
    const int t = threadIdx.x;
    int v = (t < NSB) ? bsum[t] : 0;
    sdata[t] = v;
    __syncthreads();
    for (int d = 1; d < 256; d <<= 1) {
        int u = (t >= d) ? sdata[t - d] : 0;
        __syncthreads();
        sdata[t] += u;
        __syncthreads();
    }
    if (t < NSB) bofs[t] = sdata[t] - v;
}

// ---------------------------------------------------------------- scan phase 3: offs + bucket cursors
__global__ __launch_bounds__(256) void scan3_kernel(
    const int* __restrict__ pre, const int* __restrict__ bofs,
    int* __restrict__ offs, int* __restrict__ bcur)
{
    const int i = blockIdx.x * 256 + threadIdx.x;
    if (i < N_NODES) {
        int o = pre[i] + bofs[i >> 8];
        offs[i] = o;
        if (i % DPB == 0) bcur[i / DPB] = o;   // bucket write cursor seed
    }
    if (i == 0) offs[N_NODES] = N_EDGES;
}

// ---------------------------------------------------------------- scatter phase A: coarse bucket binning
// Per block: LDS-hist 4096 edges over 500 buckets, bulk-reserve ranges,
// write packed records {src:16|dst:16, ea bf16x2} block-locally.
__global__ __launch_bounds__(256) void scatterA_kernel(
    const int* __restrict__ ei, const float* __restrict__ ea,
    int* __restrict__ bcur, uint2* __restrict__ etmp)
{
    __shared__ int cnt[NBK];
    __shared__ int base[NBK];
    const int t = threadIdx.x;
    const int e0 = blockIdx.x * SC_EPB;
    const int e1 = (e0 + SC_EPB < N_EDGES) ? e0 + SC_EPB : N_EDGES;

    for (int j = t; j < NBK; j += 256) cnt[j] = 0;
    __syncthreads();
    for (int e = e0 + t; e < e1; e += 256)
        atomicAdd(&cnt[ei[N_EDGES + e] / DPB], 1);
    __syncthreads();
    for (int j = t; j < NBK; j += 256) {
        int c = cnt[j];
        if (c) base[j] = atomicAdd(&bcur[j], c);
        cnt[j] = 0;
    }
    __syncthreads();
    for (int e = e0 + t; e < e1; e += 256) {
        int d = ei[N_EDGES + e];
        int s = ei[e];
        int b = d / DPB;
        int li = atomicAdd(&cnt[b], 1);
        uint2 r;
        r.x = (unsigned)s | ((unsigned)d << 16);
        r.y = (unsigned)f2bf(ea[(size_t)e * 2])
            | ((unsigned)f2bf(ea[(size_t)e * 2 + 1]) << 16);
        etmp[base[b] + li] = r;
    }
}

// ---------------------------------------------------------------- scatter phase B: exact dst placement
// One block per bucket: 100 LDS cursors seeded from offs; L2-local writes.
__global__ __launch_bounds__(256) void sortB_kernel(
    const int* __restrict__ offs, const uint2* __restrict__ etmp,
    uint2* __restrict__ erec)
{
    __shared__ int cur[DPB];
    const int t = threadIdx.x;
    const int b = blockIdx.x;
    const int dlo = b * DPB;
    if (t < DPB) cur[t] = offs[dlo + t];
    __syncthreads();
    const int rbeg = offs[dlo];
    const int rend = offs[dlo + DPB];   // offs[N_NODES] valid for last bucket
    for (int i = rbeg + t; i < rend; i += 256) {
        uint2 r = etmp[i];
        int d = (int)(r.x >> 16);
        int pos = atomicAdd(&cur[d - dlo], 1);
        uint2 o;
        o.x = r.x & 0xFFFFu;   // src
        o.y = r.y;             // ea bf16x2
        erec[pos] = o;
    }
}

// ---------------------------------------------------------------- layer1 attention: one wave per dst node
// 4 edges/wave (g), 16 lanes/edge (s owns channels 4s..4s+3).
__global__ __launch_bounds__(256) void attn1_kernel(
    const int* __restrict__ offs, const uint2* __restrict__ erec,
    const float* __restrict__ We,
    const float* __restrict__ q1, const unsigned short* __restrict__ kv1,
    const float* __restrict__ s1, float* __restrict__ h)
{
    int n    = (blockIdx.x * 256 + threadIdx.x) >> 6;
    int lane = threadIdx.x & 63;
    if (n >= N_NODES) return;
    const int g = lane >> 4;     // edge slot 0..3
    const int s = lane & 15;     // channel quad: channels 4s..4s+3

    const float4 qv  = *(const float4*)(q1 + (size_t)n * HC + s * 4);
    const float4 We0 = *(const float4*)(We + s * 4);
    const float4 We1 = *(const float4*)(We + HC + s * 4);
    const int beg = offs[n], end = offs[n + 1];

    float m = -3.402823466e38f, l = 0.f;
    float4 acc = make_float4(0.f, 0.f, 0.f, 0.f);

    for (int base = beg; base < end; base += 4) {
        int i = base + g;
        bool valid = (i < end);
        uint2 r = erec[valid ? i : beg];
        int src = (int)r.x;
        float ea0 = bflo(r.y), ea1 = bfhi(r.y);
        const unsigned short* kvp = kv1 + ((size_t)src << 7) + (s << 2);
        uint2 kraw = *(const uint2*)kvp;
        uint2 vraw = *(const uint2*)(kvp + 64);
        float k0 = bflo(kraw.x), k1 = bfhi(kraw.x);
        float k2 = bflo(kraw.y), k3 = bfhi(kraw.y);
        float v0 = bflo(vraw.x), v1 = bfhi(vraw.x);
        float v2 = bflo(vraw.y), v3 = bfhi(vraw.y);
        float4 ec = make_float4(ea0 * We0.x + ea1 * We1.x,
                                ea0 * We0.y + ea1 * We1.y,
                                ea0 * We0.z + ea1 * We1.z,
                                ea0 * We0.w + ea1 * We1.w);
        float d = qv.x * (k0 + ec.x) + qv.y * (k1 + ec.y)
                + qv.z * (k2 + ec.z) + qv.w * (k3 + ec.w);
        d = dpp_add4(d);                          // head dot (16 channels)
        float logit = valid ? d * 0.25f : -3.402823466e38f;   // 1/sqrt(16)
        float mn = fmaxf(m, logit);
        float sm = __expf(m - mn);
        float pe = valid ? __expf(logit - mn) : 0.f;
        l = l * sm + pe;
        acc.x = acc.x * sm + pe * (v0 + ec.x);
        acc.y = acc.y * sm + pe * (v1 + ec.y);
        acc.z = acc.z * sm + pe * (v2 + ec.z);
        acc.w = acc.w * sm + pe * (v3 + ec.w);
        m = mn;
    }

    if (end > beg) {
        float M = fmaxf(m, __shfl_xor(m, 16));
        M = fmaxf(M, __shfl_xor(M, 32));
        float sc = __expf(m - M);                 // empty group: -inf -> 0
        l *= sc; acc.x *= sc; acc.y *= sc; acc.z *= sc; acc.w *= sc;
        l += __shfl_xor(l, 16);  l += __shfl_xor(l, 32);
        acc.x += __shfl_xor(acc.x, 16); acc.x += __shfl_xor(acc.x, 32);
        acc.y += __shfl_xor(acc.y, 16); acc.y += __shfl_xor(acc.y, 32);
        acc.z += __shfl_xor(acc.z, 16); acc.z += __shfl_xor(acc.z, 32);
        acc.w += __shfl_xor(acc.w, 16); acc.w += __shfl_xor(acc.w, 32);
        if (lane < 16) {
            float inv = 1.f / l;
            float4 sk = *(const float4*)(s1 + (size_t)n * HC + s * 4);
            float4 o;
            o.x = acc.x * inv + sk.x;
            o.y = acc.y * inv + sk.y;
            o.z = acc.z * inv + sk.z;
            o.w = acc.w * inv + sk.w;
            o.x = o.x > 0.f ? o.x : expm1f(o.x);
            o.y = o.y > 0.f ? o.y : expm1f(o.y);
            o.z = o.z > 0.f ? o.z : expm1f(o.z);
            o.w = o.w > 0.f ? o.w : expm1f(o.w);
            *(float4*)(h + (size_t)n * HC + s * 4) = o;
        }
    } else if (lane < 16) {
        float4 sk = *(const float4*)(s1 + (size_t)n * HC + s * 4);
        float4 o;
        o.x = sk.x > 0.f ? sk.x : expm1f(sk.x);
        o.y = sk.y > 0.f ? sk.y : expm1f(sk.y);
        o.z = sk.z > 0.f ? sk.z : expm1f(sk.z);
        o.w = sk.w > 0.f ? sk.w : expm1f(sk.w);
        *(float4*)(h + (size_t)n * HC + s * 4) = o;
    }
}

// ---------------------------------------------------------------- layer2 node projections (64 -> 28), thread-per-node
__global__ __launch_bounds__(256) void proj2_kernel(
    const float* __restrict__ h,
    const float* __restrict__ Wq, const float* __restrict__ bq,
    const float* __restrict__ Wk, const float* __restrict__ bk,
    const float* __restrict__ Wv, const float* __restrict__ bv,
    const float* __restrict__ Ws, const float* __restrict__ bs,
    float* __restrict__ q2p, float* __restrict__ kv2, float* __restrict__ s2p)
{
    __shared__ float Wsm[HC][4][8];   // 8 KB
    __shared__ float Bsm[4][8];
    const int t = threadIdx.x;

    for (int j = t; j < HC * 28; j += 256) {
        int i = j / 28, r = j % 28, mtx = r / 7, c = r % 7;
        const float* W = (mtx == 0) ? Wq : (mtx == 1) ? Wk : (mtx == 2) ? Wv : Ws;
        Wsm[i][mtx][c] = W[i * OUTF + c];
    }
    for (int j = t; j < HC * 4; j += 256)          // zero the c=7 pad
        Wsm[j >> 2][j & 3][7] = 0.f;
    if (t < 32) {
        int mtx = t >> 3, c = t & 7;
        const float* B = (mtx == 0) ? bq : (mtx == 1) ? bk : (mtx == 2) ? bv : bs;
        Bsm[mtx][c] = (c < 7) ? B[c] : 0.f;
    }
    __syncthreads();

    int n = blockIdx.x * 256 + t;
    if (n >= N_NODES) return;

    float acc[4][8];
#pragma unroll
    for (int mtx = 0; mtx < 4; mtx++)
#pragma unroll
        for (int c = 0; c < 8; c++) acc[mtx][c] = Bsm[mtx][c];

    const float4* hp = (const float4*)(h + (size_t)n * HC);
#pragma unroll 4
    for (int i4 = 0; i4 < 16; i4++) {
        float4 hv = hp[i4];
        float hx[4] = { hv.x, hv.y, hv.z, hv.w };
#pragma unroll
        for (int e = 0; e < 4; e++) {
            int i = i4 * 4 + e;
#pragma unroll
            for (int mtx = 0; mtx < 4; mtx++) {
                float4 wa = *(const float4*)&Wsm[i][mtx][0];
                float4 wb = *(const float4*)&Wsm[i][mtx][4];
                acc[mtx][0] += hx[e] * wa.x; acc[mtx][1] += hx[e] * wa.y;
                acc[mtx][2] += hx[e] * wa.z; acc[mtx][3] += hx[e] * wa.w;
                acc[mtx][4] += hx[e] * wb.x; acc[mtx][5] += hx[e] * wb.y;
                acc[mtx][6] += hx[e] * wb.z; acc[mtx][7] += hx[e] * wb.w;
            }
        }
    }

    float4* q2v = (float4*)(q2p + (size_t)n * 8);
    q2v[0] = make_float4(acc[0][0], acc[0][1], acc[0][2], acc[0][3]);
    q2v[1] = make_float4(acc[0][4], acc[0][5], acc[0][6], acc[0][7]);
    float4* kvv = (float4*)(kv2 + (size_t)n * 16);
    kvv[0] = make_float4(acc[1][0], acc[1][1], acc[1][2], acc[1][3]);
    kvv[1] = make_float4(acc[1][4], acc[1][5], acc[1][6], acc[1][7]);
    kvv[2] = make_float4(acc[2][0], acc[2][1], acc[2][2], acc[2][3]);
    kvv[3] = make_float4(acc[2][4], acc[2][5], acc[2][6], acc[2][7]);
    float4* s2v = (float4*)(s2p + (size_t)n * 8);
    s2v[0] = make_float4(acc[3][0], acc[3][1], acc[3][2], acc[3][3]);
    s2v[1] = make_float4(acc[3][4], acc[3][5], acc[3][6], acc[3][7]);
}

// ---------------------------------------------------------------- layer2 attention: 4 nodes/wave, 16 lanes/node
__global__ __launch_bounds__(256) void attn2_kernel(
    const int* __restrict__ offs, const uint2* __restrict__ erec,
    const float* __restrict__ q2p, const float* __restrict__ kv2,
    const float* __restrict__ s2p, float* __restrict__ out)
{
    int idx = blockIdx.x * 256 + threadIdx.x;
    int n   = idx >> 4;
    int s   = idx & 15;
    if (n >= N_NODES) return;

    float4 qa = *(const float4*)(q2p + (size_t)n * 8);
    float4 qb = *(const float4*)(q2p + (size_t)n * 8 + 4);
    int beg = offs[n], end = offs[n + 1];

    float m = -3.402823466e38f, l = 0.f, a[OUTF];
#pragma unroll
    for (int c = 0; c < OUTF; c++) a[c] = 0.f;

    for (int i = beg + s; i < end; i += 16) {
        int src = (int)erec[i].x;
        const float4* kvp = (const float4*)(kv2 + (size_t)src * 16);
        float4 ka = kvp[0], kb = kvp[1], va = kvp[2], vb = kvp[3];
        float dot = qa.x * ka.x + qa.y * ka.y + qa.z * ka.z + qa.w * ka.w
                  + qb.x * kb.x + qb.y * kb.y + qb.z * kb.z;
        float logit = dot * 0.37796447300922725f;       // 1/sqrt(7)
        float mn = fmaxf(m, logit);
        float sc = __expf(m - mn);
        float pe = __expf(logit - mn);
        l = l * sc + pe;
        a[0] = a[0] * sc + pe * va.x;
        a[1] = a[1] * sc + pe * va.y;
        a[2] = a[2] * sc + pe * va.z;
        a[3] = a[3] * sc + pe * va.w;
        a[4] = a[4] * sc + pe * vb.x;
        a[5] = a[5] * sc + pe * vb.y;
        a[6] = a[6] * sc + pe * vb.z;
        m = mn;
    }

    if (end > beg) {
        float M = dpp_max16(m);                   // lanes past degree hold -inf
        float sc = __expf(m - M);                 // -inf lanes -> 0
        l *= sc;
#pragma unroll
        for (int c = 0; c < OUTF; c++) a[c] *= sc;
        l = dpp_add16(l);
#pragma unroll
        for (int c = 0; c < OUTF; c++) a[c] = dpp_add16(a[c]);
        if (s == 0) {
            float inv = 1.f / fmaxf(l, 1e-16f);
#pragma unroll
            for (int c = 0; c < OUTF; c++)
                out[(size_t)n * OUTF + c] = a[c] * inv + s2p[(size_t)n * 8 + c];
        }
    } else if (s == 0) {
#pragma unroll
        for (int c = 0; c < OUTF; c++)
            out[(size_t)n * OUTF + c] = s2p[(size_t)n * 8 + c];
    }
}

// ----------------------------------------------------------------
extern "C" void kernel_launch(void* const* d_in, const int* in_sizes, int n_in,
                              void* d_out, int out_size, void* d_ws, size_t ws_size,
                              hipStream_t stream)
{
    const float* x    = (const float*)d_in[0];
    const float* ea   = (const float*)d_in[1];
    const int*   ei   = (const int*)d_in[2];
    const float* Wq1  = (const float*)d_in[3];
    const float* bq1  = (const float*)d_in[4];
    const float* Wk1  = (const float*)d_in[5];
    const float* bk1  = (const float*)d_in[6];
    const float* Wv1  = (const float*)d_in[7];
    const float* bv1  = (const float*)d_in[8];
    const float* We1  = (const float*)d_in[9];
    const float* Ws1  = (const float*)d_in[10];
    const float* bs1  = (const float*)d_in[11];
    const float* Wq2  = (const float*)d_in[12];
    const float* bq2  = (const float*)d_in[13];
    const float* Wk2  = (const float*)d_in[14];
    const float* bk2  = (const float*)d_in[15];
    const float* Wv2  = (const float*)d_in[16];
    const float* bv2  = (const float*)d_in[17];
    const float* Ws2  = (const float*)d_in[18];
    const float* bs2  = (const float*)d_in[19];
    float* out = (float*)d_out;

    // workspace layout (f32 words); all segments 16B-aligned.
    float* ws = (float*)d_ws;
    float*          q1  = ws;                                   // N*64 f32
    float*          s1  = q1 + (size_t)N_NODES * HC;            // N*64 f32
    unsigned short* kv1 = (unsigned short*)(s1 + (size_t)N_NODES * HC); // N*128 bf16
    float*          hbuf = q1;   // alias: attn1 reads q1 row n then writes h row n
    uint2* erec = (uint2*)((float*)kv1 + (size_t)N_NODES * HC); // E x 8B
    uint2* etmp = erec + N_EDGES;                    // E x 8B
    float*  q2p  = (float*)(etmp + N_EDGES);         // N*8
    float*  kv2  = q2p + (size_t)N_NODES * 8;        // N*16
    float*  s2p  = kv2 + (size_t)N_NODES * 16;       // N*8
    unsigned short* Wt = (unsigned short*)(s2p + (size_t)N_NODES * 8);  // 32768 bf16
    int*    count  = (int*)(Wt + 4 * HC * IN_F);     // N
    int*    offs   = count + N_NODES;                // N+1
    int*    pre    = offs + N_NODES + 1;             // N
    int*    bsum   = pre + N_NODES;                  // NSB
    int*    bofs   = bsum + NSB;                     // NSB
    int*    bcur   = bofs + NSB;                     // NBK

    init_kernel<<<(N_NODES + 255) / 256, 256, 0, stream>>>(count);
    convert_w_kernel<<<(4 * HC * IN_F + 255) / 256, 256, 0, stream>>>(
        Wq1, Wk1, Wv1, Ws1, Wt);
    hist_kernel<<<(N_EDGES + 255) / 256, 256, 0, stream>>>(ei, count);

    proj1_mfma_kernel<<<N_NODES / 16, 256, 0, stream>>>(
        x, Wt, bq1, bk1, bv1, bs1, q1, kv1, s1);

    scan1_kernel<<<NSB, 256, 0, stream>>>(count, pre, bsum);
    scan2_kernel<<<1, 256, 0, stream>>>(bsum, bofs);
    scan3_kernel<<<NSB, 256, 0, stream>>>(pre, bofs, offs, bcur);

    scatterA_kernel<<<SCA_BLOCKS, 256, 0, stream>>>(ei, ea, bcur, etmp);
    sortB_kernel<<<NBK, 256, 0, stream>>>(offs, etmp, erec);

    attn1_kernel<<<(N_NODES * 64 + 255) / 256, 256, 0, stream>>>(
        offs, erec, We1, q1, kv1, s1, hbuf);

    proj2_kernel<<<(N_NODES + 255) / 256, 256, 0, stream>>>(
        hbuf, Wq2, bq2, Wk2, bk2, Wv2, bv2, Ws2, bs2, q2p, kv2, s2p);

    attn2_kernel<<<(N_NODES * 16 + 255) / 256, 256, 0, stream>>>(
        offs, erec, q2p, kv2, s2p, out);
}